// Round 4
// baseline (645.175 us; speedup 1.0000x reference)
//
#include <hip/hip_runtime.h>
#include <hip/hip_bf16.h>

// CustomTransformerBlock: B=4,S=2048,D=1024,H=16,DH=64,W=1024,DFF=4096
#define BB 4
#define SS 2048
#define DD 1024
#define HH 16
#define DHH 64
#define WW 1024
#define DFF 4096
#define MM (BB*SS)
#define NEGV (-1e10f)
// K pre-scale: log2(e)/sqrt(1024) folded into K at KV-GEMM epilogue
#define KSC 0.045084220027780106f

using f32x4 = __attribute__((ext_vector_type(4))) float;
using s16x8 = __attribute__((ext_vector_type(8))) short;
using s16x4 = __attribute__((ext_vector_type(4))) short;
using u64 = unsigned long long;

typedef const __attribute__((address_space(1))) void* gas_t;
typedef __attribute__((address_space(3))) void* las_t;

__device__ inline short f2b(float f) {
  __hip_bfloat16 h = __float2bfloat16(f);
  return __builtin_bit_cast(short, h);
}
__device__ inline float b2f(short u) {
  __hip_bfloat16 h = __builtin_bit_cast(__hip_bfloat16, u);
  return __bfloat162float(h);
}

__device__ inline void gload_lds16(const short* g, short* lds) {
  __builtin_amdgcn_global_load_lds((gas_t)g, (las_t)lds, 16, 0, 0);
}

__device__ inline f32x4 mfma16(s16x8 a, s16x8 b, f32x4 c) {
  return __builtin_amdgcn_mfma_f32_16x16x32_bf16(a, b, c, 0, 0, 0);
}

// -------------------- LayerNorm (row of 1024), out bf16 --------------------
template<int IN_BF16>
__global__ __launch_bounds__(256) void ln_kernel(const void* __restrict__ inp,
                                                 const float* __restrict__ g,
                                                 const float* __restrict__ bta,
                                                 short* __restrict__ outp) {
  int row = blockIdx.x;
  int t = threadIdx.x;
  float v[4];
  if constexpr (IN_BF16) {
    s16x4 r4 = *((const s16x4*)((const short*)inp + (size_t)row*DD) + t);
    v[0]=b2f(r4[0]); v[1]=b2f(r4[1]); v[2]=b2f(r4[2]); v[3]=b2f(r4[3]);
  } else {
    f32x4 r4 = *((const f32x4*)((const float*)inp + (size_t)row*DD) + t);
    v[0]=r4[0]; v[1]=r4[1]; v[2]=r4[2]; v[3]=r4[3];
  }
  float s = v[0]+v[1]+v[2]+v[3];
  float sq = v[0]*v[0]+v[1]*v[1]+v[2]*v[2]+v[3]*v[3];
  for (int m=1;m<64;m<<=1){ s += __shfl_xor(s,m); sq += __shfl_xor(sq,m); }
  __shared__ float red[8];
  int wv = t>>6;
  if ((t&63)==0){ red[wv]=s; red[4+wv]=sq; }
  __syncthreads();
  s  = red[0]+red[1]+red[2]+red[3];
  sq = red[4]+red[5]+red[6]+red[7];
  float mean = s*(1.f/DD);
  float rstd = rsqrtf(sq*(1.f/DD) - mean*mean + 1e-5f);
  int col = t*4;
  s16x4 o;
  #pragma unroll
  for (int j=0;j<4;++j) o[j] = f2b((v[j]-mean)*rstd*g[col+j]+bta[col+j]);
  *((s16x4*)(outp + (size_t)row*DD) + t) = o;
}

// ------------- fp32 [K][N] -> bf16 [N][K] transpose-cast (weights) ----------
__global__ __launch_bounds__(256) void transpose_cast(const float* __restrict__ in,
                                                      short* __restrict__ out,
                                                      int K, int N) {
  __shared__ float tile[32][33];
  int n0 = blockIdx.x*32, k0 = blockIdx.y*32;
  int tx = threadIdx.x & 31, ty = threadIdx.x >> 5;
  #pragma unroll
  for (int j=0;j<4;++j) tile[ty+8*j][tx] = in[(size_t)(k0+ty+8*j)*N + n0+tx];
  __syncthreads();
  #pragma unroll
  for (int j=0;j<4;++j) out[(size_t)(n0+ty+8*j)*K + k0+tx] = f2b(tile[tx][ty+8*j]);
}

// ---- pad bool(int) -> per-(b,col16) u64 bitmask: bit(c*4+nf) = pad[c*64+nf*16+col16]
__global__ void pad_bitmask(const int* __restrict__ pad, u64* __restrict__ pm) {
  int idx = threadIdx.x;            // 64 threads: b(2b) x col16(4b)
  int b_ = idx>>4, col = idx&15;
  const int* pb = pad + b_*SS + (SS-WW);
  u64 m = 0;
  for (int c=0;c<16;++c)
    for (int nf=0;nf<4;++nf)
      if (pb[c*64+nf*16+col]) m |= (1ull << (c*4+nf));
  pm[idx] = m;
}

// -------------------- GEMM: C = A[M,K] * Bt[N,K]^T + bias --------------------
// 1D grid, bijective chunked XCD swizzle (nwg%8==0). 128x128 tile, BK=32.
// EPI: 0=q(bf16), 1=kv(K scaled by KSC; V transposed), 2=ff1(silu), 3=ff2(+x f32)
template<int EPI>
__global__ __launch_bounds__(256) void gemm_bt(const short* __restrict__ A,
                                               const short* __restrict__ Bt,
                                               const float* __restrict__ bias,
                                               void* __restrict__ out1,
                                               void* __restrict__ out2,
                                               const float* __restrict__ resid,
                                               int N, int K, int lgx) {
  __shared__ short As[128*32], Bs[128*32];
  int tid = threadIdx.x, l = tid&63;
  int wv = tid>>6, wm = wv>>1, wn = wv&1;
  // chunked XCD swizzle: XCD (id%8) owns a contiguous wg range -> A-panel L2 reuse
  int q8 = gridDim.x >> 3;
  int wg = (blockIdx.x & 7)*q8 + (blockIdx.x >> 3);
  int bx = wg & ((1<<lgx)-1), by = wg >> lgx;
  const short* Ablk;
  if constexpr (EPI==1) {
    int b_ = (by*128)>>10;          // batch
    int w0 = (by*128)&1023;         // window row
    Ablk = A + ((size_t)b_*SS + (SS-WW) + w0)*DD;
  } else {
    Ablk = A + (size_t)by*128*K;
  }
  const short* Bblk = Bt + (size_t)bx*128*K;
  f32x4 acc[4][4];
  #pragma unroll
  for (int i=0;i<4;++i)
    #pragma unroll
    for(int j=0;j<4;++j)
      #pragma unroll
      for(int r=0;r<4;++r) acc[i][j][r]=0.f;
  int rA = l & 15;
  int cslot = (((l>>4) ^ ((l>>1)&3))*8);
  for (int kt=0; kt<K; kt+=32) {
    __syncthreads();
    #pragma unroll
    for (int p=0;p<2;++p) {
      int s = p*256 + tid;
      int srow = s>>2;
      int scs = (((s&3) ^ ((s>>3)&3))*8);   // pre-swizzled source slot
      gload_lds16(Ablk + (size_t)srow*K + kt + scs, &As[(p*256 + (tid & ~63))*8]);
      gload_lds16(Bblk + (size_t)srow*K + kt + scs, &Bs[(p*256 + (tid & ~63))*8]);
    }
    __syncthreads();
    s16x8 af[4], bfr[4];
    #pragma unroll
    for (int mf=0;mf<4;++mf) af[mf]  = *(const s16x8*)&As[(wm*64+mf*16+rA)*32 + cslot];
    #pragma unroll
    for (int nf=0;nf<4;++nf) bfr[nf] = *(const s16x8*)&Bs[(wn*64+nf*16+rA)*32 + cslot];
    #pragma unroll
    for (int mf=0;mf<4;++mf)
      #pragma unroll
      for (int nf=0;nf<4;++nf)
        acc[mf][nf] = mfma16(af[mf], bfr[nf], acc[mf][nf]);
  }
  #pragma unroll
  for (int mf=0;mf<4;++mf) {
    #pragma unroll
    for (int nf=0;nf<4;++nf) {
      #pragma unroll
      for (int r=0;r<4;++r) {
        int row = by*128 + wm*64 + mf*16 + ((l>>4)<<2) + r;  // C row=(l>>4)*4+r
        int col = bx*128 + wn*64 + nf*16 + (l&15);           // C col=l&15
        float v = acc[mf][nf][r] + bias[col];
        if constexpr (EPI==0) {
          ((short*)out1)[(size_t)row*N + col] = f2b(v);
        } else if constexpr (EPI==1) {
          int b_ = row>>10, w_ = row&1023;
          if (col < DD) {        // K head: [b][h][w][dh], pre-scaled by KSC
            int h = col>>6, dh = col&63;
            ((short*)out1)[(((size_t)(b_*HH+h))*WW + w_)*DHH + dh] = f2b(v*KSC);
          } else {               // V head transposed: [b][h][dh][w]
            int cc = col - DD;
            int h = cc>>6, dh = cc&63;
            ((short*)out2)[(((size_t)(b_*HH+h))*DHH + dh)*WW + w_] = f2b(v);
          }
        } else if constexpr (EPI==2) {
          float sv = v / (1.f + __expf(-v));   // silu
          ((short*)out1)[(size_t)row*N + col] = f2b(sv);
        } else {
          ((float*)out1)[(size_t)row*N + col] = v + resid[(size_t)row*N + col];
        }
      }
    }
  }
}

// -------------------- Flash attention over W=1024 keys --------------------
// 1 wave per workgroup (64 thr), 32 q-rows/wave, 4096 blocks, no barriers.
// K/V L2-resident (256KB/bh, 8 bh per XCD). Scores already in log2 domain
// (K pre-scaled by KSC) -> exp2. Defer-max with reduce-free trigger.
struct KF { s16x8 v[4][2]; };

__global__ __launch_bounds__(64,4) void attn_kernel(const short* __restrict__ q,
    const short* __restrict__ kpan, const short* __restrict__ vtpan,
    const u64* __restrict__ pmarr, short* __restrict__ outp) {
  __shared__ short P[32*72];
  int l = threadIdx.x;
  // XCD-aware: all 64 q-tiles of one (b,h) on one XCD, heavy tiles first.
  int id = blockIdx.x;
  int xcd = id & 7, slot = id >> 3;
  int bh = xcd + 8*(slot >> 6);        // 0..63 (= b*16+h)
  int u  = 63 - (slot & 63);           // 32-row tile, heavy-first
  int bb = bh >> 4, h = bh & 15;
  int r0 = u*32;
  const short* kbase = kpan + (size_t)bh*WW*DHH;
  const short* vbase = vtpan + (size_t)bh*DHH*WW;
  u64 pmask = pmarr[bb*16 + (l&15)];
  const s16x8 ones8 = { 0x3F80,0x3F80,0x3F80,0x3F80,0x3F80,0x3F80,0x3F80,0x3F80 };

  s16x8 aq[2][2];
  #pragma unroll
  for (int g=0;g<2;++g)
    #pragma unroll
    for (int kf=0;kf<2;++kf)
      aq[g][kf] = *(const s16x8*)(q + ((size_t)bb*SS + r0 + g*16 + (l&15))*DD
                                    + h*DHH + (l>>4)*8 + kf*32);
  f32x4 oacc[2][4];
  float mrun[2][4], lrun[2][4], scale[2][4];
  #pragma unroll
  for (int g=0;g<2;++g)
    #pragma unroll
    for (int i=0;i<4;++i) {
      #pragma unroll
      for (int r=0;r<4;++r) oacc[g][i][r]=0.f;
      mrun[g][i]=-INFINITY; lrun[g][i]=0.f;
    }
  int dchunk = u>>1;
  int nch = dchunk+1 < 16 ? dchunk+1 : 16;

  auto loadK = [&](int c, KF& d) {
    const short* kc = kbase + (size_t)c*64*DHH;
    #pragma unroll
    for (int nf=0;nf<4;++nf) {
      const short* p = kc + (size_t)(nf*16+(l&15))*DHH + ((l>>4)*8);
      d.v[nf][0] = *(const s16x8*)p;
      d.v[nf][1] = *(const s16x8*)(p+32);
    }
  };

  auto body = [&](int c, KF& kf) {
    // ---- QK^T (scores pre-scaled to log2 domain) ----
    f32x4 sc[2][4];
    #pragma unroll
    for (int g=0;g<2;++g)
      #pragma unroll
      for (int nf=0;nf<4;++nf)
        #pragma unroll
        for (int r=0;r<4;++r) sc[g][nf][r]=0.f;
    __builtin_amdgcn_s_setprio(1);
    #pragma unroll
    for (int nf=0;nf<4;++nf)
      #pragma unroll
      for (int g=0;g<2;++g) {
        sc[g][nf] = mfma16(aq[g][0], kf.v[nf][0], sc[g][nf]);
        sc[g][nf] = mfma16(aq[g][1], kf.v[nf][1], sc[g][nf]);
      }
    __builtin_amdgcn_s_setprio(0);
    // ---- mask (exact NEG) + per-lane partial max ----
    int diag = (c >= dchunk);
    float pm[2][4];
    #pragma unroll
    for (int g=0;g<2;++g)
      #pragma unroll
      for (int r=0;r<4;++r) pm[g][r] = -INFINITY;
    #pragma unroll
    for (int nf=0;nf<4;++nf) {
      int j = c*64 + nf*16 + (l&15);
      int padj = (int)((pmask >> (c*4+nf)) & 1ull);
      #pragma unroll
      for (int g=0;g<2;++g)
        #pragma unroll
        for (int r=0;r<4;++r) {
          float xv = padj ? NEGV : sc[g][nf][r];
          if (diag) {
            int sq_ = r0 + g*16 + ((l>>4)<<2) + r;
            xv = (j > sq_) ? NEGV : xv;
          }
          sc[g][nf][r] = xv;
          pm[g][r] = fmaxf(pm[g][r], xv);
        }
    }
    // ---- defer-max: reduce-free trigger (partial max ~ row max under __any) ----
    int need = 0;
    #pragma unroll
    for (int g=0;g<2;++g)
      #pragma unroll
      for (int r=0;r<4;++r) need |= (pm[g][r] > mrun[g][r] + 12.f) ? 1 : 0;
    #pragma unroll
    for (int g=0;g<2;++g)
      #pragma unroll
      for (int r=0;r<4;++r) scale[g][r] = 1.f;
    if (__any(need)) {
      #pragma unroll
      for (int m=1;m<16;m<<=1)
        #pragma unroll
        for (int g=0;g<2;++g)
          #pragma unroll
          for (int r=0;r<4;++r) pm[g][r] = fmaxf(pm[g][r], __shfl_xor(pm[g][r], m));
      #pragma unroll
      for (int g=0;g<2;++g)
        #pragma unroll
        for (int r=0;r<4;++r) {
          float mn = fmaxf(mrun[g][r], pm[g][r]);
          scale[g][r] = exp2f(mrun[g][r]-mn);
          mrun[g][r] = mn;
        }
      #pragma unroll
      for (int g=0;g<2;++g)
        #pragma unroll
        for (int nf=0;nf<4;++nf)
          #pragma unroll
          for (int r=0;r<4;++r) oacc[g][nf][r] *= scale[g][r];
    }
    // ---- p = exp2(s - m), P -> LDS ----
    #pragma unroll
    for (int nf=0;nf<4;++nf)
      #pragma unroll
      for (int g=0;g<2;++g)
        #pragma unroll
        for (int r=0;r<4;++r)
          sc[g][nf][r] = exp2f(sc[g][nf][r]-mrun[g][r]);
    #pragma unroll
    for (int g=0;g<2;++g)
      #pragma unroll
      for (int nf=0;nf<4;++nf)
        #pragma unroll
        for (int r=0;r<4;++r)
          P[(g*16+((l>>4)<<2)+r)*72 + nf*16 + (l&15)] = f2b(sc[g][nf][r]);
    // ---- PV + row-sum(ones) MFMA, V from L2 ----
    f32x4 ls2[2];
    #pragma unroll
    for (int g=0;g<2;++g)
      #pragma unroll
      for (int r=0;r<4;++r) ls2[g][r]=0.f;
    __builtin_amdgcn_s_setprio(1);
    #pragma unroll
    for (int ks=0;ks<2;++ks) {
      s16x8 ap[2];
      #pragma unroll
      for (int g=0;g<2;++g) {
        ap[g] = *(const s16x8*)&P[(g*16+(l&15))*72 + ks*32 + ((l>>4)*8)];
        ls2[g] = mfma16(ap[g], ones8, ls2[g]);
      }
      #pragma unroll
      for (int nf=0;nf<4;++nf) {
        s16x8 bv = *(const s16x8*)(vbase + (size_t)(nf*16+(l&15))*WW
                                   + c*64 + ks*32 + ((l>>4)*8));
        #pragma unroll
        for (int g=0;g<2;++g)
          oacc[g][nf] = mfma16(ap[g], bv, oacc[g][nf]);
      }
    }
    __builtin_amdgcn_s_setprio(0);
    #pragma unroll
    for (int g=0;g<2;++g)
      #pragma unroll
      for (int r=0;r<4;++r) lrun[g][r] = lrun[g][r]*scale[g][r] + ls2[g][r];
  };

  KF ka, kb;
  loadK(0, ka);
  int cend = nch, c = 0, ext = 0;
  while (true) {
    if (c == cend) {
      if (ext) break;
      ext = 1;
      // fully-padded rows must softmax uniformly over ALL 1024 keys
      int dead = 0;
      #pragma unroll
      for (int g=0;g<2;++g)
        #pragma unroll
        for (int r=0;r<4;++r) dead |= (mrun[g][r] < -5e9f) ? 1 : 0;
      if (!__any(dead)) break;
      cend = 16;
      if (c >= 16) break;
    }
    if (c+1 < 16) loadK(c+1, kb);   // prefetch next chunk's K (L2-hit)
    body(c, ka);
    ka = kb;
    ++c;
  }

  #pragma unroll
  for (int g=0;g<2;++g)
    #pragma unroll
    for (int nf=0;nf<4;++nf)
      #pragma unroll
      for (int r=0;r<4;++r) {
        int srow = r0 + g*16 + ((l>>4)<<2) + r;
        float o = oacc[g][nf][r] / lrun[g][r];
        outp[((size_t)bb*SS + srow)*DD + h*DHH + nf*16 + (l&15)] = f2b(o);
      }
}

// -------------------- driver --------------------
extern "C" void kernel_launch(void* const* d_in, const int* in_sizes, int n_in,
                              void* d_out, int out_size, void* d_ws, size_t ws_size,
                              hipStream_t stream) {
  const float* x    = (const float*)d_in[0];
  const int*   pad  = (const int*)d_in[1];   // bool mask as int32 on device
  const float* ln1g = (const float*)d_in[2];
  const float* ln1b = (const float*)d_in[3];
  const float* wq   = (const float*)d_in[4];
  const float* bq   = (const float*)d_in[5];
  const float* wkv  = (const float*)d_in[6];
  const float* bkv  = (const float*)d_in[7];
  const float* ln2g = (const float*)d_in[8];
  const float* ln2b = (const float*)d_in[9];
  const float* w1   = (const float*)d_in[10];
  const float* b1   = (const float*)d_in[11];
  const float* w2   = (const float*)d_in[12];
  const float* b2   = (const float*)d_in[13];

  char* ws = (char*)d_ws;
  const size_t MB = 1024*1024;
  short* ln1x = (short*)(ws + 0);        // 16MB, dead after KV gemm
  short* qb   = (short*)(ws + 16*MB);    // 16MB, dead after attn
  short* kpan = (short*)(ws + 32*MB);    //  8MB, dead after attn
  short* vtp  = (short*)(ws + 40*MB);    //  8MB, dead after attn
  u64*   pmar = (u64*)  (ws + 48*MB);    //  512B
  short* h1   = (short*)(ws + 0);        // 64MB, reuses [0,64MB) after attn
  short* outb = (short*)(ws + 64*MB);    // 16MB attn out
  short* hb   = (short*)(ws + 80*MB);    // 16MB ln2 out
  short* wqT  = (short*)(ws + 96*MB);    //  2MB
  short* wkvT = (short*)(ws + 98*MB);    //  4MB
  short* w1T  = (short*)(ws + 102*MB);   //  8MB
  short* w2T  = (short*)(ws + 110*MB);   //  8MB  (total 118MB)

  pad_bitmask<<<1,64,0,stream>>>(pad, pmar);
  transpose_cast<<<dim3(32,32),  256,0,stream>>>(wq,  wqT,  1024, 1024);
  transpose_cast<<<dim3(64,32),  256,0,stream>>>(wkv, wkvT, 1024, 2048);
  transpose_cast<<<dim3(128,32), 256,0,stream>>>(w1,  w1T,  1024, 4096);
  transpose_cast<<<dim3(32,128), 256,0,stream>>>(w2,  w2T,  4096, 1024);
  ln_kernel<0><<<MM,256,0,stream>>>(x, ln1g, ln1b, ln1x);
  gemm_bt<0><<<512, 256,0,stream>>>(ln1x, wqT,  bq,  qb,   nullptr, nullptr, 1024, 1024, 3);
  gemm_bt<1><<<512, 256,0,stream>>>(ln1x, wkvT, bkv, kpan, vtp,     nullptr, 2048, 1024, 4);
  attn_kernel<<<4096,64,0,stream>>>(qb, kpan, vtp, pmar, outb);
  ln_kernel<1><<<MM,256,0,stream>>>(outb, ln2g, ln2b, hb);
  gemm_bt<2><<<2048,256,0,stream>>>(hb, w1T, b1, h1,    nullptr, nullptr, 4096, 1024, 5);
  gemm_bt<3><<<512, 256,0,stream>>>(h1, w2T, b2, d_out, nullptr, x,       1024, 4096, 3);
}

// Round 5
// 441.528 us; speedup vs baseline: 1.4612x; 1.4612x over previous
//
#include <hip/hip_runtime.h>
#include <hip/hip_bf16.h>

// CustomTransformerBlock: B=4,S=2048,D=1024,H=16,DH=64,W=1024,DFF=4096
#define BB 4
#define SS 2048
#define DD 1024
#define HH 16
#define DHH 64
#define WW 1024
#define DFF 4096
#define MM (BB*SS)
#define NEGV (-1e10f)
// K pre-scale: log2(e)/sqrt(1024) folded into K at KV-GEMM epilogue
#define KSC 0.045084220027780106f

using f32x4 = __attribute__((ext_vector_type(4))) float;
using s16x8 = __attribute__((ext_vector_type(8))) short;
using s16x4 = __attribute__((ext_vector_type(4))) short;
using u64 = unsigned long long;

typedef const __attribute__((address_space(1))) void* gas_t;
typedef __attribute__((address_space(3))) void* las_t;

__device__ inline short f2b(float f) {
  __hip_bfloat16 h = __float2bfloat16(f);
  return __builtin_bit_cast(short, h);
}
__device__ inline float b2f(short u) {
  __hip_bfloat16 h = __builtin_bit_cast(__hip_bfloat16, u);
  return __bfloat162float(h);
}

__device__ inline void gload_lds16(const short* g, short* lds) {
  __builtin_amdgcn_global_load_lds((gas_t)g, (las_t)lds, 16, 0, 0);
}

__device__ inline f32x4 mfma16(s16x8 a, s16x8 b, f32x4 c) {
  return __builtin_amdgcn_mfma_f32_16x16x32_bf16(a, b, c, 0, 0, 0);
}

// -------------------- LayerNorm (row of 1024), out bf16 --------------------
template<int IN_BF16>
__global__ __launch_bounds__(256) void ln_kernel(const void* __restrict__ inp,
                                                 const float* __restrict__ g,
                                                 const float* __restrict__ bta,
                                                 short* __restrict__ outp) {
  int row = blockIdx.x;
  int t = threadIdx.x;
  float v[4];
  if constexpr (IN_BF16) {
    s16x4 r4 = *((const s16x4*)((const short*)inp + (size_t)row*DD) + t);
    v[0]=b2f(r4[0]); v[1]=b2f(r4[1]); v[2]=b2f(r4[2]); v[3]=b2f(r4[3]);
  } else {
    f32x4 r4 = *((const f32x4*)((const float*)inp + (size_t)row*DD) + t);
    v[0]=r4[0]; v[1]=r4[1]; v[2]=r4[2]; v[3]=r4[3];
  }
  float s = v[0]+v[1]+v[2]+v[3];
  float sq = v[0]*v[0]+v[1]*v[1]+v[2]*v[2]+v[3]*v[3];
  for (int m=1;m<64;m<<=1){ s += __shfl_xor(s,m); sq += __shfl_xor(sq,m); }
  __shared__ float red[8];
  int wv = t>>6;
  if ((t&63)==0){ red[wv]=s; red[4+wv]=sq; }
  __syncthreads();
  s  = red[0]+red[1]+red[2]+red[3];
  sq = red[4]+red[5]+red[6]+red[7];
  float mean = s*(1.f/DD);
  float rstd = rsqrtf(sq*(1.f/DD) - mean*mean + 1e-5f);
  int col = t*4;
  s16x4 o;
  #pragma unroll
  for (int j=0;j<4;++j) o[j] = f2b((v[j]-mean)*rstd*g[col+j]+bta[col+j]);
  *((s16x4*)(outp + (size_t)row*DD) + t) = o;
}

// ------------- fp32 [K][N] -> bf16 [N][K] transpose-cast (weights) ----------
__global__ __launch_bounds__(256) void transpose_cast(const float* __restrict__ in,
                                                      short* __restrict__ out,
                                                      int K, int N) {
  __shared__ float tile[32][33];
  int n0 = blockIdx.x*32, k0 = blockIdx.y*32;
  int tx = threadIdx.x & 31, ty = threadIdx.x >> 5;
  #pragma unroll
  for (int j=0;j<4;++j) tile[ty+8*j][tx] = in[(size_t)(k0+ty+8*j)*N + n0+tx];
  __syncthreads();
  #pragma unroll
  for (int j=0;j<4;++j) out[(size_t)(n0+ty+8*j)*K + k0+tx] = f2b(tile[tx][ty+8*j]);
}

// ---- pad bool(int) -> per-(b,col16) u64 bitmask: bit(c*4+nf) = pad[c*64+nf*16+col16]
__global__ void pad_bitmask(const int* __restrict__ pad, u64* __restrict__ pm) {
  int idx = threadIdx.x;            // 64 threads: b(2b) x col16(4b)
  int b_ = idx>>4, col = idx&15;
  const int* pb = pad + b_*SS + (SS-WW);
  u64 m = 0;
  for (int c=0;c<16;++c)
    for (int nf=0;nf<4;++nf)
      if (pb[c*64+nf*16+col]) m |= (1ull << (c*4+nf));
  pm[idx] = m;
}

// -------------------- GEMM: C = A[M,K] * Bt[N,K]^T + bias --------------------
// 1D grid, bijective chunked XCD swizzle (nwg%8==0). 128x128 tile, BK=32.
// EPI: 0=q(bf16), 1=kv(K scaled by KSC; V transposed), 2=ff1(silu), 3=ff2(+x f32)
template<int EPI>
__global__ __launch_bounds__(256) void gemm_bt(const short* __restrict__ A,
                                               const short* __restrict__ Bt,
                                               const float* __restrict__ bias,
                                               void* __restrict__ out1,
                                               void* __restrict__ out2,
                                               const float* __restrict__ resid,
                                               int N, int K, int lgx) {
  __shared__ short As[128*32], Bs[128*32];
  int tid = threadIdx.x, l = tid&63;
  int wv = tid>>6, wm = wv>>1, wn = wv&1;
  // chunked XCD swizzle: XCD (id%8) owns a contiguous wg range -> A-panel L2 reuse
  int q8 = gridDim.x >> 3;
  int wg = (blockIdx.x & 7)*q8 + (blockIdx.x >> 3);
  int bx = wg & ((1<<lgx)-1), by = wg >> lgx;
  const short* Ablk;
  if constexpr (EPI==1) {
    int b_ = (by*128)>>10;          // batch
    int w0 = (by*128)&1023;         // window row
    Ablk = A + ((size_t)b_*SS + (SS-WW) + w0)*DD;
  } else {
    Ablk = A + (size_t)by*128*K;
  }
  const short* Bblk = Bt + (size_t)bx*128*K;
  f32x4 acc[4][4];
  #pragma unroll
  for (int i=0;i<4;++i)
    #pragma unroll
    for(int j=0;j<4;++j)
      #pragma unroll
      for(int r=0;r<4;++r) acc[i][j][r]=0.f;
  int rA = l & 15;
  int cslot = (((l>>4) ^ ((l>>1)&3))*8);
  for (int kt=0; kt<K; kt+=32) {
    __syncthreads();
    #pragma unroll
    for (int p=0;p<2;++p) {
      int s = p*256 + tid;
      int srow = s>>2;
      int scs = (((s&3) ^ ((s>>3)&3))*8);   // pre-swizzled source slot
      gload_lds16(Ablk + (size_t)srow*K + kt + scs, &As[(p*256 + (tid & ~63))*8]);
      gload_lds16(Bblk + (size_t)srow*K + kt + scs, &Bs[(p*256 + (tid & ~63))*8]);
    }
    __syncthreads();
    s16x8 af[4], bfr[4];
    #pragma unroll
    for (int mf=0;mf<4;++mf) af[mf]  = *(const s16x8*)&As[(wm*64+mf*16+rA)*32 + cslot];
    #pragma unroll
    for (int nf=0;nf<4;++nf) bfr[nf] = *(const s16x8*)&Bs[(wn*64+nf*16+rA)*32 + cslot];
    #pragma unroll
    for (int mf=0;mf<4;++mf)
      #pragma unroll
      for (int nf=0;nf<4;++nf)
        acc[mf][nf] = mfma16(af[mf], bfr[nf], acc[mf][nf]);
  }
  #pragma unroll
  for (int mf=0;mf<4;++mf) {
    #pragma unroll
    for (int nf=0;nf<4;++nf) {
      #pragma unroll
      for (int r=0;r<4;++r) {
        int row = by*128 + wm*64 + mf*16 + ((l>>4)<<2) + r;  // C row=(l>>4)*4+r
        int col = bx*128 + wn*64 + nf*16 + (l&15);           // C col=l&15
        float v = acc[mf][nf][r] + bias[col];
        if constexpr (EPI==0) {
          ((short*)out1)[(size_t)row*N + col] = f2b(v);
        } else if constexpr (EPI==1) {
          int b_ = row>>10, w_ = row&1023;
          if (col < DD) {        // K head: [b][h][w][dh], pre-scaled by KSC
            int h = col>>6, dh = col&63;
            ((short*)out1)[(((size_t)(b_*HH+h))*WW + w_)*DHH + dh] = f2b(v*KSC);
          } else {               // V head transposed: [b][h][dh][w]
            int cc = col - DD;
            int h = cc>>6, dh = cc&63;
            ((short*)out2)[(((size_t)(b_*HH+h))*DHH + dh)*WW + w_] = f2b(v);
          }
        } else if constexpr (EPI==2) {
          float sv = v / (1.f + __expf(-v));   // silu
          ((short*)out1)[(size_t)row*N + col] = f2b(sv);
        } else {
          ((float*)out1)[(size_t)row*N + col] = v + resid[(size_t)row*N + col];
        }
      }
    }
  }
}

// -------------------- Flash attention over W=1024 keys --------------------
// 1 wave per workgroup (64 thr), 32 q-rows/wave, 4096 blocks, no barriers.
// K/V L2-resident (256KB/bh, 8 bh per XCD). Scores already in log2 domain
// (K pre-scaled by KSC) -> exp2. Defer-max with reduce-free trigger.
// launch_bounds (64,2): 256-VGPR cap -- (64,4)'s 128 cap caused 1.2GB of
// scratch spill traffic (R4: FETCH 517MB, WRITE 647MB, 331us).
struct KF { s16x8 v[4][2]; };

__global__ __launch_bounds__(64,2) void attn_kernel(const short* __restrict__ q,
    const short* __restrict__ kpan, const short* __restrict__ vtpan,
    const u64* __restrict__ pmarr, short* __restrict__ outp) {
  __shared__ short P[32*72];
  int l = threadIdx.x;
  // XCD-aware: all 64 q-tiles of one (b,h) on one XCD, heavy tiles first.
  int id = blockIdx.x;
  int xcd = id & 7, slot = id >> 3;
  int bh = xcd + 8*(slot >> 6);        // 0..63 (= b*16+h)
  int u  = 63 - (slot & 63);           // 32-row tile, heavy-first
  int bb = bh >> 4, h = bh & 15;
  int r0 = u*32;
  const short* kbase = kpan + (size_t)bh*WW*DHH;
  const short* vbase = vtpan + (size_t)bh*DHH*WW;
  u64 pmask = pmarr[bb*16 + (l&15)];
  const s16x8 ones8 = { 0x3F80,0x3F80,0x3F80,0x3F80,0x3F80,0x3F80,0x3F80,0x3F80 };

  s16x8 aq[2][2];
  #pragma unroll
  for (int g=0;g<2;++g)
    #pragma unroll
    for (int kf=0;kf<2;++kf)
      aq[g][kf] = *(const s16x8*)(q + ((size_t)bb*SS + r0 + g*16 + (l&15))*DD
                                    + h*DHH + (l>>4)*8 + kf*32);
  f32x4 oacc[2][4];
  float mrun[2][4], lrun[2][4], scale[2][4];
  #pragma unroll
  for (int g=0;g<2;++g)
    #pragma unroll
    for (int i=0;i<4;++i) {
      #pragma unroll
      for (int r=0;r<4;++r) oacc[g][i][r]=0.f;
      mrun[g][i]=-INFINITY; lrun[g][i]=0.f;
    }
  int dchunk = u>>1;
  int nch = dchunk+1 < 16 ? dchunk+1 : 16;

  auto loadK = [&](int c, KF& d) {
    const short* kc = kbase + (size_t)c*64*DHH;
    #pragma unroll
    for (int nf=0;nf<4;++nf) {
      const short* p = kc + (size_t)(nf*16+(l&15))*DHH + ((l>>4)*8);
      d.v[nf][0] = *(const s16x8*)p;
      d.v[nf][1] = *(const s16x8*)(p+32);
    }
  };

  auto body = [&](int c, KF& kf) {
    // ---- QK^T (scores pre-scaled to log2 domain) ----
    f32x4 sc[2][4];
    #pragma unroll
    for (int g=0;g<2;++g)
      #pragma unroll
      for (int nf=0;nf<4;++nf)
        #pragma unroll
        for (int r=0;r<4;++r) sc[g][nf][r]=0.f;
    __builtin_amdgcn_s_setprio(1);
    #pragma unroll
    for (int nf=0;nf<4;++nf)
      #pragma unroll
      for (int g=0;g<2;++g) {
        sc[g][nf] = mfma16(aq[g][0], kf.v[nf][0], sc[g][nf]);
        sc[g][nf] = mfma16(aq[g][1], kf.v[nf][1], sc[g][nf]);
      }
    __builtin_amdgcn_s_setprio(0);
    // ---- mask (exact NEG) + per-lane partial max ----
    int diag = (c >= dchunk);
    float pm[2][4];
    #pragma unroll
    for (int g=0;g<2;++g)
      #pragma unroll
      for (int r=0;r<4;++r) pm[g][r] = -INFINITY;
    #pragma unroll
    for (int nf=0;nf<4;++nf) {
      int j = c*64 + nf*16 + (l&15);
      int padj = (int)((pmask >> (c*4+nf)) & 1ull);
      #pragma unroll
      for (int g=0;g<2;++g)
        #pragma unroll
        for (int r=0;r<4;++r) {
          float xv = padj ? NEGV : sc[g][nf][r];
          if (diag) {
            int sq_ = r0 + g*16 + ((l>>4)<<2) + r;
            xv = (j > sq_) ? NEGV : xv;
          }
          sc[g][nf][r] = xv;
          pm[g][r] = fmaxf(pm[g][r], xv);
        }
    }
    // ---- defer-max: reduce-free trigger (partial max ~ row max under __any) ----
    int need = 0;
    #pragma unroll
    for (int g=0;g<2;++g)
      #pragma unroll
      for (int r=0;r<4;++r) need |= (pm[g][r] > mrun[g][r] + 12.f) ? 1 : 0;
    #pragma unroll
    for (int g=0;g<2;++g)
      #pragma unroll
      for (int r=0;r<4;++r) scale[g][r] = 1.f;
    if (__any(need)) {
      #pragma unroll
      for (int m=1;m<16;m<<=1)
        #pragma unroll
        for (int g=0;g<2;++g)
          #pragma unroll
          for (int r=0;r<4;++r) pm[g][r] = fmaxf(pm[g][r], __shfl_xor(pm[g][r], m));
      #pragma unroll
      for (int g=0;g<2;++g)
        #pragma unroll
        for (int r=0;r<4;++r) {
          float mn = fmaxf(mrun[g][r], pm[g][r]);
          scale[g][r] = exp2f(mrun[g][r]-mn);
          mrun[g][r] = mn;
        }
      #pragma unroll
      for (int g=0;g<2;++g)
        #pragma unroll
        for (int nf=0;nf<4;++nf)
          #pragma unroll
          for (int r=0;r<4;++r) oacc[g][nf][r] *= scale[g][r];
    }
    // ---- p = exp2(s - m), P -> LDS ----
    #pragma unroll
    for (int nf=0;nf<4;++nf)
      #pragma unroll
      for (int g=0;g<2;++g)
        #pragma unroll
        for (int r=0;r<4;++r)
          sc[g][nf][r] = exp2f(sc[g][nf][r]-mrun[g][r]);
    #pragma unroll
    for (int g=0;g<2;++g)
      #pragma unroll
      for (int nf=0;nf<4;++nf)
        #pragma unroll
        for (int r=0;r<4;++r)
          P[(g*16+((l>>4)<<2)+r)*72 + nf*16 + (l&15)] = f2b(sc[g][nf][r]);
    // ---- PV + row-sum(ones) MFMA, V from L2 ----
    f32x4 ls2[2];
    #pragma unroll
    for (int g=0;g<2;++g)
      #pragma unroll
      for (int r=0;r<4;++r) ls2[g][r]=0.f;
    __builtin_amdgcn_s_setprio(1);
    #pragma unroll
    for (int ks=0;ks<2;++ks) {
      s16x8 ap[2];
      #pragma unroll
      for (int g=0;g<2;++g) {
        ap[g] = *(const s16x8*)&P[(g*16+(l&15))*72 + ks*32 + ((l>>4)*8)];
        ls2[g] = mfma16(ap[g], ones8, ls2[g]);
      }
      #pragma unroll
      for (int nf=0;nf<4;++nf) {
        s16x8 bv = *(const s16x8*)(vbase + (size_t)(nf*16+(l&15))*WW
                                   + c*64 + ks*32 + ((l>>4)*8));
        #pragma unroll
        for (int g=0;g<2;++g)
          oacc[g][nf] = mfma16(ap[g], bv, oacc[g][nf]);
      }
    }
    __builtin_amdgcn_s_setprio(0);
    #pragma unroll
    for (int g=0;g<2;++g)
      #pragma unroll
      for (int r=0;r<4;++r) lrun[g][r] = lrun[g][r]*scale[g][r] + ls2[g][r];
  };

  KF ka, kb;
  loadK(0, ka);
  int cend = nch, c = 0, ext = 0;
  while (true) {
    if (c == cend) {
      if (ext) break;
      ext = 1;
      // fully-padded rows must softmax uniformly over ALL 1024 keys
      int dead = 0;
      #pragma unroll
      for (int g=0;g<2;++g)
        #pragma unroll
        for (int r=0;r<4;++r) dead |= (mrun[g][r] < -5e9f) ? 1 : 0;
      if (!__any(dead)) break;
      cend = 16;
      if (c >= 16) break;
    }
    if (c+1 < 16) loadK(c+1, kb);   // prefetch next chunk's K (L2-hit)
    body(c, ka);
    ka = kb;
    ++c;
  }

  #pragma unroll
  for (int g=0;g<2;++g)
    #pragma unroll
    for (int nf=0;nf<4;++nf)
      #pragma unroll
      for (int r=0;r<4;++r) {
        int srow = r0 + g*16 + ((l>>4)<<2) + r;
        float o = oacc[g][nf][r] / lrun[g][r];
        outp[((size_t)bb*SS + srow)*DD + h*DHH + nf*16 + (l&15)] = f2b(o);
      }
}

// -------------------- driver --------------------
extern "C" void kernel_launch(void* const* d_in, const int* in_sizes, int n_in,
                              void* d_out, int out_size, void* d_ws, size_t ws_size,
                              hipStream_t stream) {
  const float* x    = (const float*)d_in[0];
  const int*   pad  = (const int*)d_in[1];   // bool mask as int32 on device
  const float* ln1g = (const float*)d_in[2];
  const float* ln1b = (const float*)d_in[3];
  const float* wq   = (const float*)d_in[4];
  const float* bq   = (const float*)d_in[5];
  const float* wkv  = (const float*)d_in[6];
  const float* bkv  = (const float*)d_in[7];
  const float* ln2g = (const float*)d_in[8];
  const float* ln2b = (const float*)d_in[9];
  const float* w1   = (const float*)d_in[10];
  const float* b1   = (const float*)d_in[11];
  const float* w2   = (const float*)d_in[12];
  const float* b2   = (const float*)d_in[13];

  char* ws = (char*)d_ws;
  const size_t MB = 1024*1024;
  short* ln1x = (short*)(ws + 0);        // 16MB, dead after KV gemm
  short* qb   = (short*)(ws + 16*MB);    // 16MB, dead after attn
  short* kpan = (short*)(ws + 32*MB);    //  8MB, dead after attn
  short* vtp  = (short*)(ws + 40*MB);    //  8MB, dead after attn
  u64*   pmar = (u64*)  (ws + 48*MB);    //  512B
  short* h1   = (short*)(ws + 0);        // 64MB, reuses [0,64MB) after attn
  short* outb = (short*)(ws + 64*MB);    // 16MB attn out
  short* hb   = (short*)(ws + 80*MB);    // 16MB ln2 out
  short* wqT  = (short*)(ws + 96*MB);    //  2MB
  short* wkvT = (short*)(ws + 98*MB);    //  4MB
  short* w1T  = (short*)(ws + 102*MB);   //  8MB
  short* w2T  = (short*)(ws + 110*MB);   //  8MB  (total 118MB)

  pad_bitmask<<<1,64,0,stream>>>(pad, pmar);
  transpose_cast<<<dim3(32,32),  256,0,stream>>>(wq,  wqT,  1024, 1024);
  transpose_cast<<<dim3(64,32),  256,0,stream>>>(wkv, wkvT, 1024, 2048);
  transpose_cast<<<dim3(128,32), 256,0,stream>>>(w1,  w1T,  1024, 4096);
  transpose_cast<<<dim3(32,128), 256,0,stream>>>(w2,  w2T,  4096, 1024);
  ln_kernel<0><<<MM,256,0,stream>>>(x, ln1g, ln1b, ln1x);
  gemm_bt<0><<<512, 256,0,stream>>>(ln1x, wqT,  bq,  qb,   nullptr, nullptr, 1024, 1024, 3);
  gemm_bt<1><<<512, 256,0,stream>>>(ln1x, wkvT, bkv, kpan, vtp,     nullptr, 2048, 1024, 4);
  attn_kernel<<<4096,64,0,stream>>>(qb, kpan, vtp, pmar, outb);
  ln_kernel<1><<<MM,256,0,stream>>>(outb, ln2g, ln2b, hb);
  gemm_bt<2><<<2048,256,0,stream>>>(hb, w1T, b1, h1,    nullptr, nullptr, 4096, 1024, 5);
  gemm_bt<3><<<512, 256,0,stream>>>(h1, w2T, b2, d_out, nullptr, x,       1024, 4096, 3);
}

// Round 6
// 437.372 us; speedup vs baseline: 1.4751x; 1.0095x over previous
//
#include <hip/hip_runtime.h>
#include <hip/hip_bf16.h>

// CustomTransformerBlock: B=4,S=2048,D=1024,H=16,DH=64,W=1024,DFF=4096
#define BB 4
#define SS 2048
#define DD 1024
#define HH 16
#define DHH 64
#define WW 1024
#define DFF 4096
#define MM (BB*SS)
#define NEGV (-1e10f)
// K pre-scale: log2(e)/sqrt(1024) folded into K at KV-GEMM epilogue
#define KSC 0.045084220027780106f

using f32x4 = __attribute__((ext_vector_type(4))) float;
using s16x8 = __attribute__((ext_vector_type(8))) short;
using s16x4 = __attribute__((ext_vector_type(4))) short;
using u64 = unsigned long long;

typedef const __attribute__((address_space(1))) void* gas_t;
typedef __attribute__((address_space(3))) void* las_t;

__device__ inline short f2b(float f) {
  __hip_bfloat16 h = __float2bfloat16(f);
  return __builtin_bit_cast(short, h);
}
__device__ inline float b2f(short u) {
  __hip_bfloat16 h = __builtin_bit_cast(__hip_bfloat16, u);
  return __bfloat162float(h);
}

__device__ inline void gload_lds16(const short* g, short* lds) {
  __builtin_amdgcn_global_load_lds((gas_t)g, (las_t)lds, 16, 0, 0);
}

__device__ inline f32x4 mfma16(s16x8 a, s16x8 b, f32x4 c) {
  return __builtin_amdgcn_mfma_f32_16x16x32_bf16(a, b, c, 0, 0, 0);
}

// -------------------- LayerNorm (row of 1024), out bf16 --------------------
template<int IN_BF16>
__global__ __launch_bounds__(256) void ln_kernel(const void* __restrict__ inp,
                                                 const float* __restrict__ g,
                                                 const float* __restrict__ bta,
                                                 short* __restrict__ outp) {
  int row = blockIdx.x;
  int t = threadIdx.x;
  float v[4];
  if constexpr (IN_BF16) {
    s16x4 r4 = *((const s16x4*)((const short*)inp + (size_t)row*DD) + t);
    v[0]=b2f(r4[0]); v[1]=b2f(r4[1]); v[2]=b2f(r4[2]); v[3]=b2f(r4[3]);
  } else {
    f32x4 r4 = *((const f32x4*)((const float*)inp + (size_t)row*DD) + t);
    v[0]=r4[0]; v[1]=r4[1]; v[2]=r4[2]; v[3]=r4[3];
  }
  float s = v[0]+v[1]+v[2]+v[3];
  float sq = v[0]*v[0]+v[1]*v[1]+v[2]*v[2]+v[3]*v[3];
  for (int m=1;m<64;m<<=1){ s += __shfl_xor(s,m); sq += __shfl_xor(sq,m); }
  __shared__ float red[8];
  int wv = t>>6;
  if ((t&63)==0){ red[wv]=s; red[4+wv]=sq; }
  __syncthreads();
  s  = red[0]+red[1]+red[2]+red[3];
  sq = red[4]+red[5]+red[6]+red[7];
  float mean = s*(1.f/DD);
  float rstd = rsqrtf(sq*(1.f/DD) - mean*mean + 1e-5f);
  int col = t*4;
  s16x4 o;
  #pragma unroll
  for (int j=0;j<4;++j) o[j] = f2b((v[j]-mean)*rstd*g[col+j]+bta[col+j]);
  *((s16x4*)(outp + (size_t)row*DD) + t) = o;
}

// ------------- fp32 [K][N] -> bf16 [N][K] transpose-cast (weights) ----------
__global__ __launch_bounds__(256) void transpose_cast(const float* __restrict__ in,
                                                      short* __restrict__ out,
                                                      int K, int N) {
  __shared__ float tile[32][33];
  int n0 = blockIdx.x*32, k0 = blockIdx.y*32;
  int tx = threadIdx.x & 31, ty = threadIdx.x >> 5;
  #pragma unroll
  for (int j=0;j<4;++j) tile[ty+8*j][tx] = in[(size_t)(k0+ty+8*j)*N + n0+tx];
  __syncthreads();
  #pragma unroll
  for (int j=0;j<4;++j) out[(size_t)(n0+ty+8*j)*K + k0+tx] = f2b(tile[tx][ty+8*j]);
}

// ---- pad bool(int) -> per-(b,col16) u64 bitmask: bit(c*4+nf) = pad[c*64+nf*16+col16]
__global__ void pad_bitmask(const int* __restrict__ pad, u64* __restrict__ pm) {
  int idx = threadIdx.x;            // 64 threads: b(2b) x col16(4b)
  int b_ = idx>>4, col = idx&15;
  const int* pb = pad + b_*SS + (SS-WW);
  u64 m = 0;
  for (int c=0;c<16;++c)
    for (int nf=0;nf<4;++nf)
      if (pb[c*64+nf*16+col]) m |= (1ull << (c*4+nf));
  pm[idx] = m;
}

// -------------------- GEMM: C = A[M,K] * Bt[N,K]^T + bias --------------------
// 1D grid, bijective chunked XCD swizzle (nwg%8==0). 128x128 tile, BK=32.
// EPI: 0=q(bf16), 1=kv(K scaled by KSC; V transposed), 2=ff1(silu), 3=ff2(+x f32)
template<int EPI>
__global__ __launch_bounds__(256) void gemm_bt(const short* __restrict__ A,
                                               const short* __restrict__ Bt,
                                               const float* __restrict__ bias,
                                               void* __restrict__ out1,
                                               void* __restrict__ out2,
                                               const float* __restrict__ resid,
                                               int N, int K, int lgx) {
  __shared__ short As[128*32], Bs[128*32];
  int tid = threadIdx.x, l = tid&63;
  int wv = tid>>6, wm = wv>>1, wn = wv&1;
  // chunked XCD swizzle: XCD (id%8) owns a contiguous wg range -> A-panel L2 reuse
  int q8 = gridDim.x >> 3;
  int wg = (blockIdx.x & 7)*q8 + (blockIdx.x >> 3);
  int bx = wg & ((1<<lgx)-1), by = wg >> lgx;
  const short* Ablk;
  if constexpr (EPI==1) {
    int b_ = (by*128)>>10;          // batch
    int w0 = (by*128)&1023;         // window row
    Ablk = A + ((size_t)b_*SS + (SS-WW) + w0)*DD;
  } else {
    Ablk = A + (size_t)by*128*K;
  }
  const short* Bblk = Bt + (size_t)bx*128*K;
  f32x4 acc[4][4];
  #pragma unroll
  for (int i=0;i<4;++i)
    #pragma unroll
    for(int j=0;j<4;++j)
      #pragma unroll
      for(int r=0;r<4;++r) acc[i][j][r]=0.f;
  int rA = l & 15;
  int cslot = (((l>>4) ^ ((l>>1)&3))*8);
  for (int kt=0; kt<K; kt+=32) {
    __syncthreads();
    #pragma unroll
    for (int p=0;p<2;++p) {
      int s = p*256 + tid;
      int srow = s>>2;
      int scs = (((s&3) ^ ((s>>3)&3))*8);   // pre-swizzled source slot
      gload_lds16(Ablk + (size_t)srow*K + kt + scs, &As[(p*256 + (tid & ~63))*8]);
      gload_lds16(Bblk + (size_t)srow*K + kt + scs, &Bs[(p*256 + (tid & ~63))*8]);
    }
    __syncthreads();
    s16x8 af[4], bfr[4];
    #pragma unroll
    for (int mf=0;mf<4;++mf) af[mf]  = *(const s16x8*)&As[(wm*64+mf*16+rA)*32 + cslot];
    #pragma unroll
    for (int nf=0;nf<4;++nf) bfr[nf] = *(const s16x8*)&Bs[(wn*64+nf*16+rA)*32 + cslot];
    #pragma unroll
    for (int mf=0;mf<4;++mf)
      #pragma unroll
      for (int nf=0;nf<4;++nf)
        acc[mf][nf] = mfma16(af[mf], bfr[nf], acc[mf][nf]);
  }
  #pragma unroll
  for (int mf=0;mf<4;++mf) {
    #pragma unroll
    for (int nf=0;nf<4;++nf) {
      #pragma unroll
      for (int r=0;r<4;++r) {
        int row = by*128 + wm*64 + mf*16 + ((l>>4)<<2) + r;  // C row=(l>>4)*4+r
        int col = bx*128 + wn*64 + nf*16 + (l&15);           // C col=l&15
        float v = acc[mf][nf][r] + bias[col];
        if constexpr (EPI==0) {
          ((short*)out1)[(size_t)row*N + col] = f2b(v);
        } else if constexpr (EPI==1) {
          int b_ = row>>10, w_ = row&1023;
          if (col < DD) {        // K head: [b][h][w][dh], pre-scaled by KSC
            int h = col>>6, dh = col&63;
            ((short*)out1)[(((size_t)(b_*HH+h))*WW + w_)*DHH + dh] = f2b(v*KSC);
          } else {               // V head transposed: [b][h][dh][w]
            int cc = col - DD;
            int h = cc>>6, dh = cc&63;
            ((short*)out2)[(((size_t)(b_*HH+h))*DHH + dh)*WW + w_] = f2b(v);
          }
        } else if constexpr (EPI==2) {
          float sv = v / (1.f + __expf(-v));   // silu
          ((short*)out1)[(size_t)row*N + col] = f2b(sv);
        } else {
          ((float*)out1)[(size_t)row*N + col] = v + resid[(size_t)row*N + col];
        }
      }
    }
  }
}

// -------------------- Flash attention over W=1024 keys --------------------
// 1 wave per workgroup (64 thr), 32 q-rows/wave, 4096 blocks, no barriers.
// K/V L2-resident. Scores in log2 domain (K pre-scaled by KSC) -> exp2.
// R6: V issued EARLY (split ks halves, covered by exp2/P-phase); mask loop
// unswitched on diag (non-diag chunks = pad-only masking).
struct KF { s16x8 v[4][2]; };

__global__ __launch_bounds__(64,2) void attn_kernel(const short* __restrict__ q,
    const short* __restrict__ kpan, const short* __restrict__ vtpan,
    const u64* __restrict__ pmarr, short* __restrict__ outp) {
  __shared__ short P[32*72];
  int l = threadIdx.x;
  // XCD-aware: all 64 q-tiles of one (b,h) on one XCD, heavy tiles first.
  int id = blockIdx.x;
  int xcd = id & 7, slot = id >> 3;
  int bh = xcd + 8*(slot >> 6);        // 0..63 (= b*16+h)
  int u  = 63 - (slot & 63);           // 32-row tile, heavy-first
  int bb = bh >> 4, h = bh & 15;
  int r0 = u*32;
  const short* kbase = kpan + (size_t)bh*WW*DHH;
  const short* vbase = vtpan + (size_t)bh*DHH*WW;
  u64 pmask = pmarr[bb*16 + (l&15)];
  const s16x8 ones8 = { 0x3F80,0x3F80,0x3F80,0x3F80,0x3F80,0x3F80,0x3F80,0x3F80 };

  s16x8 aq[2][2];
  #pragma unroll
  for (int g=0;g<2;++g)
    #pragma unroll
    for (int kf=0;kf<2;++kf)
      aq[g][kf] = *(const s16x8*)(q + ((size_t)bb*SS + r0 + g*16 + (l&15))*DD
                                    + h*DHH + (l>>4)*8 + kf*32);
  f32x4 oacc[2][4];
  float mrun[2][4], lrun[2][4], scale[2][4];
  #pragma unroll
  for (int g=0;g<2;++g)
    #pragma unroll
    for (int i=0;i<4;++i) {
      #pragma unroll
      for (int r=0;r<4;++r) oacc[g][i][r]=0.f;
      mrun[g][i]=-INFINITY; lrun[g][i]=0.f;
    }
  int dchunk = u>>1;
  int nch = dchunk+1 < 16 ? dchunk+1 : 16;

  auto loadK = [&](int c, KF& d) {
    const short* kc = kbase + (size_t)c*64*DHH;
    #pragma unroll
    for (int nf=0;nf<4;++nf) {
      const short* p = kc + (size_t)(nf*16+(l&15))*DHH + ((l>>4)*8);
      d.v[nf][0] = *(const s16x8*)p;
      d.v[nf][1] = *(const s16x8*)(p+32);
    }
  };

  auto body = [&](int c, KF& kf) {
    // ---- QK^T (scores pre-scaled to log2 domain) ----
    f32x4 sc[2][4];
    #pragma unroll
    for (int g=0;g<2;++g)
      #pragma unroll
      for (int nf=0;nf<4;++nf)
        #pragma unroll
        for (int r=0;r<4;++r) sc[g][nf][r]=0.f;
    __builtin_amdgcn_s_setprio(1);
    #pragma unroll
    for (int nf=0;nf<4;++nf)
      #pragma unroll
      for (int g=0;g<2;++g) {
        sc[g][nf] = mfma16(aq[g][0], kf.v[nf][0], sc[g][nf]);
        sc[g][nf] = mfma16(aq[g][1], kf.v[nf][1], sc[g][nf]);
      }
    __builtin_amdgcn_s_setprio(0);
    // ---- mask (exact NEG), unswitched on diag ----
    unsigned nib = (unsigned)(pmask >> (c*4)) & 15u;
    float pm[2][4];
    #pragma unroll
    for (int g=0;g<2;++g)
      #pragma unroll
      for (int r=0;r<4;++r) pm[g][r] = -INFINITY;
    if (c >= dchunk) {               // diagonal / future: pad + causal
      #pragma unroll
      for (int nf=0;nf<4;++nf) {
        int j = c*64 + nf*16 + (l&15);
        int padj = (int)((nib>>nf)&1u);
        #pragma unroll
        for (int g=0;g<2;++g)
          #pragma unroll
          for (int r=0;r<4;++r) {
            int sq_ = r0 + g*16 + ((l>>4)<<2) + r;
            float xv = (padj || (j > sq_)) ? NEGV : sc[g][nf][r];
            sc[g][nf][r] = xv;
            pm[g][r] = fmaxf(pm[g][r], xv);
          }
      }
    } else {                          // interior: pad-only
      #pragma unroll
      for (int nf=0;nf<4;++nf) {
        int padj = (int)((nib>>nf)&1u);
        #pragma unroll
        for (int g=0;g<2;++g)
          #pragma unroll
          for (int r=0;r<4;++r) {
            float xv = padj ? NEGV : sc[g][nf][r];
            sc[g][nf][r] = xv;
            pm[g][r] = fmaxf(pm[g][r], xv);
          }
      }
    }
    // ---- V ks=0 half issued early: covered by defer-check + exp2 ----
    s16x8 vf0[4], vf1[4];
    #pragma unroll
    for (int nf=0;nf<4;++nf)
      vf0[nf] = *(const s16x8*)(vbase + (size_t)(nf*16+(l&15))*WW
                                + c*64 + ((l>>4)*8));
    // ---- defer-max: reduce-free trigger ----
    int need = 0;
    #pragma unroll
    for (int g=0;g<2;++g)
      #pragma unroll
      for (int r=0;r<4;++r) need |= (pm[g][r] > mrun[g][r] + 12.f) ? 1 : 0;
    #pragma unroll
    for (int g=0;g<2;++g)
      #pragma unroll
      for (int r=0;r<4;++r) scale[g][r] = 1.f;
    if (__any(need)) {
      #pragma unroll
      for (int m=1;m<16;m<<=1)
        #pragma unroll
        for (int g=0;g<2;++g)
          #pragma unroll
          for (int r=0;r<4;++r) pm[g][r] = fmaxf(pm[g][r], __shfl_xor(pm[g][r], m));
      #pragma unroll
      for (int g=0;g<2;++g)
        #pragma unroll
        for (int r=0;r<4;++r) {
          float mn = fmaxf(mrun[g][r], pm[g][r]);
          scale[g][r] = exp2f(mrun[g][r]-mn);
          mrun[g][r] = mn;
        }
      #pragma unroll
      for (int g=0;g<2;++g)
        #pragma unroll
        for (int nf=0;nf<4;++nf)
          #pragma unroll
          for (int r=0;r<4;++r) oacc[g][nf][r] *= scale[g][r];
    }
    // ---- p = exp2(s - m) ----
    #pragma unroll
    for (int nf=0;nf<4;++nf)
      #pragma unroll
      for (int g=0;g<2;++g)
        #pragma unroll
        for (int r=0;r<4;++r)
          sc[g][nf][r] = exp2f(sc[g][nf][r]-mrun[g][r]);
    // ---- V ks=1 half issued here: covered by P write+read ----
    #pragma unroll
    for (int nf=0;nf<4;++nf)
      vf1[nf] = *(const s16x8*)(vbase + (size_t)(nf*16+(l&15))*WW
                                + c*64 + 32 + ((l>>4)*8));
    // ---- P -> LDS (bf16) ----
    #pragma unroll
    for (int g=0;g<2;++g)
      #pragma unroll
      for (int nf=0;nf<4;++nf)
        #pragma unroll
        for (int r=0;r<4;++r)
          P[(g*16+((l>>4)<<2)+r)*72 + nf*16 + (l&15)] = f2b(sc[g][nf][r]);
    // ---- PV + row-sum(ones) MFMA ----
    f32x4 ls2[2];
    #pragma unroll
    for (int g=0;g<2;++g)
      #pragma unroll
      for (int r=0;r<4;++r) ls2[g][r]=0.f;
    __builtin_amdgcn_s_setprio(1);
    #pragma unroll
    for (int ks=0;ks<2;++ks) {
      s16x8 ap[2];
      #pragma unroll
      for (int g=0;g<2;++g) {
        ap[g] = *(const s16x8*)&P[(g*16+(l&15))*72 + ks*32 + ((l>>4)*8)];
        ls2[g] = mfma16(ap[g], ones8, ls2[g]);
      }
      #pragma unroll
      for (int nf=0;nf<4;++nf) {
        s16x8 bv = ks ? vf1[nf] : vf0[nf];
        #pragma unroll
        for (int g=0;g<2;++g)
          oacc[g][nf] = mfma16(ap[g], bv, oacc[g][nf]);
      }
    }
    __builtin_amdgcn_s_setprio(0);
    #pragma unroll
    for (int g=0;g<2;++g)
      #pragma unroll
      for (int r=0;r<4;++r) lrun[g][r] = lrun[g][r]*scale[g][r] + ls2[g][r];
  };

  KF ka, kb;
  loadK(0, ka);
  int cend = nch, c = 0, ext = 0;
  while (true) {
    if (c == cend) {
      if (ext) break;
      ext = 1;
      // fully-padded rows must softmax uniformly over ALL 1024 keys
      int dead = 0;
      #pragma unroll
      for (int g=0;g<2;++g)
        #pragma unroll
        for (int r=0;r<4;++r) dead |= (mrun[g][r] < -5e9f) ? 1 : 0;
      if (!__any(dead)) break;
      cend = 16;
      if (c >= 16) break;
    }
    if (c+1 < 16) loadK(c+1, kb);   // prefetch next chunk's K (L2-hit)
    body(c, ka);
    ka = kb;
    ++c;
  }

  #pragma unroll
  for (int g=0;g<2;++g)
    #pragma unroll
    for (int nf=0;nf<4;++nf)
      #pragma unroll
      for (int r=0;r<4;++r) {
        int srow = r0 + g*16 + ((l>>4)<<2) + r;
        float o = oacc[g][nf][r] / lrun[g][r];
        outp[((size_t)bb*SS + srow)*DD + h*DHH + nf*16 + (l&15)] = f2b(o);
      }
}

// -------------------- driver --------------------
extern "C" void kernel_launch(void* const* d_in, const int* in_sizes, int n_in,
                              void* d_out, int out_size, void* d_ws, size_t ws_size,
                              hipStream_t stream) {
  const float* x    = (const float*)d_in[0];
  const int*   pad  = (const int*)d_in[1];   // bool mask as int32 on device
  const float* ln1g = (const float*)d_in[2];
  const float* ln1b = (const float*)d_in[3];
  const float* wq   = (const float*)d_in[4];
  const float* bq   = (const float*)d_in[5];
  const float* wkv  = (const float*)d_in[6];
  const float* bkv  = (const float*)d_in[7];
  const float* ln2g = (const float*)d_in[8];
  const float* ln2b = (const float*)d_in[9];
  const float* w1   = (const float*)d_in[10];
  const float* b1   = (const float*)d_in[11];
  const float* w2   = (const float*)d_in[12];
  const float* b2   = (const float*)d_in[13];

  char* ws = (char*)d_ws;
  const size_t MB = 1024*1024;
  short* ln1x = (short*)(ws + 0);        // 16MB, dead after KV gemm
  short* qb   = (short*)(ws + 16*MB);    // 16MB, dead after attn
  short* kpan = (short*)(ws + 32*MB);    //  8MB, dead after attn
  short* vtp  = (short*)(ws + 40*MB);    //  8MB, dead after attn
  u64*   pmar = (u64*)  (ws + 48*MB);    //  512B
  short* h1   = (short*)(ws + 0);        // 64MB, reuses [0,64MB) after attn
  short* outb = (short*)(ws + 64*MB);    // 16MB attn out
  short* hb   = (short*)(ws + 80*MB);    // 16MB ln2 out
  short* wqT  = (short*)(ws + 96*MB);    //  2MB
  short* wkvT = (short*)(ws + 98*MB);    //  4MB
  short* w1T  = (short*)(ws + 102*MB);   //  8MB
  short* w2T  = (short*)(ws + 110*MB);   //  8MB  (total 118MB)

  pad_bitmask<<<1,64,0,stream>>>(pad, pmar);
  transpose_cast<<<dim3(32,32),  256,0,stream>>>(wq,  wqT,  1024, 1024);
  transpose_cast<<<dim3(64,32),  256,0,stream>>>(wkv, wkvT, 1024, 2048);
  transpose_cast<<<dim3(128,32), 256,0,stream>>>(w1,  w1T,  1024, 4096);
  transpose_cast<<<dim3(32,128), 256,0,stream>>>(w2,  w2T,  4096, 1024);
  ln_kernel<0><<<MM,256,0,stream>>>(x, ln1g, ln1b, ln1x);
  gemm_bt<0><<<512, 256,0,stream>>>(ln1x, wqT,  bq,  qb,   nullptr, nullptr, 1024, 1024, 3);
  gemm_bt<1><<<512, 256,0,stream>>>(ln1x, wkvT, bkv, kpan, vtp,     nullptr, 2048, 1024, 4);
  attn_kernel<<<4096,64,0,stream>>>(qb, kpan, vtp, pmar, outb);
  ln_kernel<1><<<MM,256,0,stream>>>(outb, ln2g, ln2b, hb);
  gemm_bt<2><<<2048,256,0,stream>>>(hb, w1T, b1, h1,    nullptr, nullptr, 4096, 1024, 5);
  gemm_bt<3><<<512, 256,0,stream>>>(h1, w2T, b2, d_out, nullptr, x,       1024, 4096, 3);
}

// Round 7
// 403.401 us; speedup vs baseline: 1.5993x; 1.0842x over previous
//
#include <hip/hip_runtime.h>
#include <hip/hip_bf16.h>

// CustomTransformerBlock: B=4,S=2048,D=1024,H=16,DH=64,W=1024,DFF=4096
#define BB 4
#define SS 2048
#define DD 1024
#define HH 16
#define DHH 64
#define WW 1024
#define DFF 4096
#define MM (BB*SS)
#define NEGV (-1e10f)
// K pre-scale: log2(e)/sqrt(1024) folded into K at KV-GEMM epilogue
#define KSC 0.045084220027780106f

using f32x4 = __attribute__((ext_vector_type(4))) float;
using s16x8 = __attribute__((ext_vector_type(8))) short;
using s16x4 = __attribute__((ext_vector_type(4))) short;
using u64 = unsigned long long;

typedef const __attribute__((address_space(1))) void* gas_t;
typedef __attribute__((address_space(3))) void* las_t;

__device__ inline short f2b(float f) {
  __hip_bfloat16 h = __float2bfloat16(f);
  return __builtin_bit_cast(short, h);
}
__device__ inline float b2f(short u) {
  __hip_bfloat16 h = __builtin_bit_cast(__hip_bfloat16, u);
  return __bfloat162float(h);
}

__device__ inline void gload_lds16(const short* g, short* lds) {
  __builtin_amdgcn_global_load_lds((gas_t)g, (las_t)lds, 16, 0, 0);
}

__device__ inline f32x4 mfma16(s16x8 a, s16x8 b, f32x4 c) {
  return __builtin_amdgcn_mfma_f32_16x16x32_bf16(a, b, c, 0, 0, 0);
}

// -------------------- LayerNorm (row of 1024), out bf16 --------------------
template<int IN_BF16>
__global__ __launch_bounds__(256) void ln_kernel(const void* __restrict__ inp,
                                                 const float* __restrict__ g,
                                                 const float* __restrict__ bta,
                                                 short* __restrict__ outp) {
  int row = blockIdx.x;
  int t = threadIdx.x;
  float v[4];
  if constexpr (IN_BF16) {
    s16x4 r4 = *((const s16x4*)((const short*)inp + (size_t)row*DD) + t);
    v[0]=b2f(r4[0]); v[1]=b2f(r4[1]); v[2]=b2f(r4[2]); v[3]=b2f(r4[3]);
  } else {
    f32x4 r4 = *((const f32x4*)((const float*)inp + (size_t)row*DD) + t);
    v[0]=r4[0]; v[1]=r4[1]; v[2]=r4[2]; v[3]=r4[3];
  }
  float s = v[0]+v[1]+v[2]+v[3];
  float sq = v[0]*v[0]+v[1]*v[1]+v[2]*v[2]+v[3]*v[3];
  for (int m=1;m<64;m<<=1){ s += __shfl_xor(s,m); sq += __shfl_xor(sq,m); }
  __shared__ float red[8];
  int wv = t>>6;
  if ((t&63)==0){ red[wv]=s; red[4+wv]=sq; }
  __syncthreads();
  s  = red[0]+red[1]+red[2]+red[3];
  sq = red[4]+red[5]+red[6]+red[7];
  float mean = s*(1.f/DD);
  float rstd = rsqrtf(sq*(1.f/DD) - mean*mean + 1e-5f);
  int col = t*4;
  s16x4 o;
  #pragma unroll
  for (int j=0;j<4;++j) o[j] = f2b((v[j]-mean)*rstd*g[col+j]+bta[col+j]);
  *((s16x4*)(outp + (size_t)row*DD) + t) = o;
}

// ------------- fp32 [K][N] -> bf16 [N][K] transpose-cast (weights) ----------
__global__ __launch_bounds__(256) void transpose_cast(const float* __restrict__ in,
                                                      short* __restrict__ out,
                                                      int K, int N) {
  __shared__ float tile[32][33];
  int n0 = blockIdx.x*32, k0 = blockIdx.y*32;
  int tx = threadIdx.x & 31, ty = threadIdx.x >> 5;
  #pragma unroll
  for (int j=0;j<4;++j) tile[ty+8*j][tx] = in[(size_t)(k0+ty+8*j)*N + n0+tx];
  __syncthreads();
  #pragma unroll
  for (int j=0;j<4;++j) out[(size_t)(n0+ty+8*j)*K + k0+tx] = f2b(tile[tx][ty+8*j]);
}

// ---- pad bool(int) -> per-(b,col16) u64 bitmask: bit(c*4+nf) = pad[c*64+nf*16+col16]
__global__ void pad_bitmask(const int* __restrict__ pad, u64* __restrict__ pm) {
  int idx = threadIdx.x;            // 64 threads: b(2b) x col16(4b)
  int b_ = idx>>4, col = idx&15;
  const int* pb = pad + b_*SS + (SS-WW);
  u64 m = 0;
  for (int c=0;c<16;++c)
    for (int nf=0;nf<4;++nf)
      if (pb[c*64+nf*16+col]) m |= (1ull << (c*4+nf));
  pm[idx] = m;
}

// -------------------- GEMM: C = A[M,K] * Bt[N,K]^T + bias --------------------
// 1D grid, bijective chunked XCD swizzle (nwg%8==0). 128x128 tile, BK=32.
// EPI: 0=q(bf16), 1=kv(K scaled by KSC; V transposed), 2=ff1(silu), 3=ff2(+x f32)
template<int EPI>
__global__ __launch_bounds__(256) void gemm_bt(const short* __restrict__ A,
                                               const short* __restrict__ Bt,
                                               const float* __restrict__ bias,
                                               void* __restrict__ out1,
                                               void* __restrict__ out2,
                                               const float* __restrict__ resid,
                                               int N, int K, int lgx) {
  __shared__ short As[128*32], Bs[128*32];
  int tid = threadIdx.x, l = tid&63;
  int wv = tid>>6, wm = wv>>1, wn = wv&1;
  // chunked XCD swizzle: XCD (id%8) owns a contiguous wg range -> A-panel L2 reuse
  int q8 = gridDim.x >> 3;
  int wg = (blockIdx.x & 7)*q8 + (blockIdx.x >> 3);
  int bx = wg & ((1<<lgx)-1), by = wg >> lgx;
  const short* Ablk;
  if constexpr (EPI==1) {
    int b_ = (by*128)>>10;          // batch
    int w0 = (by*128)&1023;         // window row
    Ablk = A + ((size_t)b_*SS + (SS-WW) + w0)*DD;
  } else {
    Ablk = A + (size_t)by*128*K;
  }
  const short* Bblk = Bt + (size_t)bx*128*K;
  f32x4 acc[4][4];
  #pragma unroll
  for (int i=0;i<4;++i)
    #pragma unroll
    for(int j=0;j<4;++j)
      #pragma unroll
      for(int r=0;r<4;++r) acc[i][j][r]=0.f;
  int rA = l & 15;
  int cslot = (((l>>4) ^ ((l>>1)&3))*8);
  for (int kt=0; kt<K; kt+=32) {
    __syncthreads();
    #pragma unroll
    for (int p=0;p<2;++p) {
      int s = p*256 + tid;
      int srow = s>>2;
      int scs = (((s&3) ^ ((s>>3)&3))*8);   // pre-swizzled source slot
      gload_lds16(Ablk + (size_t)srow*K + kt + scs, &As[(p*256 + (tid & ~63))*8]);
      gload_lds16(Bblk + (size_t)srow*K + kt + scs, &Bs[(p*256 + (tid & ~63))*8]);
    }
    __syncthreads();
    s16x8 af[4], bfr[4];
    #pragma unroll
    for (int mf=0;mf<4;++mf) af[mf]  = *(const s16x8*)&As[(wm*64+mf*16+rA)*32 + cslot];
    #pragma unroll
    for (int nf=0;nf<4;++nf) bfr[nf] = *(const s16x8*)&Bs[(wn*64+nf*16+rA)*32 + cslot];
    #pragma unroll
    for (int mf=0;mf<4;++mf)
      #pragma unroll
      for (int nf=0;nf<4;++nf)
        acc[mf][nf] = mfma16(af[mf], bfr[nf], acc[mf][nf]);
  }
  #pragma unroll
  for (int mf=0;mf<4;++mf) {
    #pragma unroll
    for (int nf=0;nf<4;++nf) {
      #pragma unroll
      for (int r=0;r<4;++r) {
        int row = by*128 + wm*64 + mf*16 + ((l>>4)<<2) + r;  // C row=(l>>4)*4+r
        int col = bx*128 + wn*64 + nf*16 + (l&15);           // C col=l&15
        float v = acc[mf][nf][r] + bias[col];
        if constexpr (EPI==0) {
          ((short*)out1)[(size_t)row*N + col] = f2b(v);
        } else if constexpr (EPI==1) {
          int b_ = row>>10, w_ = row&1023;
          if (col < DD) {        // K head: [b][h][w][dh], pre-scaled by KSC
            int h = col>>6, dh = col&63;
            ((short*)out1)[(((size_t)(b_*HH+h))*WW + w_)*DHH + dh] = f2b(v*KSC);
          } else {               // V head transposed: [b][h][dh][w]
            int cc = col - DD;
            int h = cc>>6, dh = cc&63;
            ((short*)out2)[(((size_t)(b_*HH+h))*DHH + dh)*WW + w_] = f2b(v);
          }
        } else if constexpr (EPI==2) {
          float sv = v / (1.f + __expf(-v));   // silu
          ((short*)out1)[(size_t)row*N + col] = f2b(sv);
        } else {
          ((float*)out1)[(size_t)row*N + col] = v + resid[(size_t)row*N + col];
        }
      }
    }
  }
}

// ---------- 256x256 8-wave GEMM, BK=32, 4-phase counted-vmcnt schedule ------
// Regions: A0|B0|A1|B1, 16KB each (64KB static LDS, 2 blocks/CU).
// Per phase: {ds_read frags; stage 1 region (2x gload_lds); s_barrier;
//             setprio(1) 16 MFMA setprio(0); [vmcnt(2) at ph1/ph3] s_barrier}.
// Rotation (iter i computes tiles t0=2i [b0], t0+1 [b1]):
//   ph0 stages A(b1)<-t0+1, ph1 B(b0)<-t0+2, ph2 A(b0)<-t0+2, ph3 B(b1)<-t0+3.
// Each region re-staged exactly one phase after its last reader's barrier;
// vmcnt(2)+barrier at ph1/ph3 close guarantees all-waves completion of the
// regions read two phases later. Never drains vmcnt to 0 in the loop (T4).
template<int EPI>
__global__ __launch_bounds__(512,2) void gemm256(const short* __restrict__ A,
                                                 const short* __restrict__ Bt,
                                                 const float* __restrict__ bias,
                                                 void* __restrict__ out1,
                                                 int N, int K, int lgx) {
  __shared__ short lds[32768];   // 64KB
  int tid = threadIdx.x, l = tid&63, wid = tid>>6;
  int wm = wid>>2, wn = wid&3;
  int q8 = gridDim.x >> 3;
  int wg = (blockIdx.x & 7)*q8 + (blockIdx.x >> 3);
  int bx = wg & ((1<<lgx)-1), by = wg >> lgx;
  const short* Ablk = A + (size_t)by*256*K;
  const short* Bblk = Bt + (size_t)bx*256*K;
  int rA = l & 15;
  int slot_s = ((l>>4) ^ ((rA>>1)&3))*8;         // short slot within 32-col row
  int aBase = (wm*128 + rA)*32 + slot_s;          // shorts
  int bBase = (wn*64  + rA)*32 + slot_s + 8192;   // B region offset
  int qs = (tid&3) ^ ((tid>>3)&3);                // pre-swizzled source slot
  const short* srcA = Ablk + (size_t)(tid>>2)*K + qs*8;
  const short* srcB = Bblk + (size_t)(tid>>2)*K + qs*8;
  int dst0 = (tid & ~63)*8;                       // wave-uniform dest (shorts)
  int nt = K >> 5;
  f32x4 acc[8][4];
  #pragma unroll
  for (int i=0;i<8;++i)
    #pragma unroll
    for (int j=0;j<4;++j)
      #pragma unroll
      for (int r=0;r<4;++r) acc[i][j][r]=0.f;

  auto stage = [&](int isB, int b, int t) {
    const short* s = isB ? srcB : srcA;
    short* d = &lds[b*16384 + isB*8192 + dst0];
    gload_lds16(s + t*32,                 d);
    gload_lds16(s + (size_t)128*K + t*32, d + 4096);
  };
  s16x8 af[4], bf[4];
  auto readA = [&](int b, int mg) {
    #pragma unroll
    for (int j=0;j<4;++j) af[j] = *(const s16x8*)&lds[b*16384 + aBase + (mg*4+j)*512];
  };
  auto readB = [&](int b) {
    #pragma unroll
    for (int j=0;j<4;++j) bf[j] = *(const s16x8*)&lds[b*16384 + bBase + j*512];
  };
  auto mfmas = [&](int mg) {
    __builtin_amdgcn_s_setprio(1);
    #pragma unroll
    for (int j=0;j<4;++j)
      #pragma unroll
      for (int nf=0;nf<4;++nf)
        acc[mg*4+j][nf] = mfma16(af[j], bf[nf], acc[mg*4+j][nf]);
    __builtin_amdgcn_s_setprio(0);
  };

  // prologue: A(b0)<-t0, B(b0)<-t0, B(b1)<-t1
  stage(0,0,0); stage(1,0,0); stage(1,1,1);
  asm volatile("s_waitcnt vmcnt(2)" ::: "memory");
  __builtin_amdgcn_s_barrier();

  for (int it = 0; it < (nt>>1); ++it) {
    int t0 = 2*it;
    int t2 = t0+2; if (t2 >= nt) t2 -= nt;   // tail stages wrap (garbage-safe)
    int t3 = t0+3; if (t3 >= nt) t3 -= nt;
    // ph0: compute tile t0 (b0, mg0)
    readB(0); readA(0,0);
    stage(0,1,t0+1);
    __builtin_amdgcn_s_barrier();
    mfmas(0);
    __builtin_amdgcn_s_barrier();
    // ph1: (b0, mg1)
    readA(0,1);
    stage(1,0,t2);
    __builtin_amdgcn_s_barrier();
    mfmas(1);
    asm volatile("s_waitcnt vmcnt(2)" ::: "memory");
    __builtin_amdgcn_s_barrier();
    // ph2: tile t0+1 (b1, mg0)
    readB(1); readA(1,0);
    stage(0,0,t2);
    __builtin_amdgcn_s_barrier();
    mfmas(0);
    __builtin_amdgcn_s_barrier();
    // ph3: (b1, mg1)
    readA(1,1);
    stage(1,1,t3);
    __builtin_amdgcn_s_barrier();
    mfmas(1);
    asm volatile("s_waitcnt vmcnt(2)" ::: "memory");
    __builtin_amdgcn_s_barrier();
  }
  asm volatile("s_waitcnt vmcnt(0)" ::: "memory");

  #pragma unroll
  for (int mf=0;mf<8;++mf) {
    #pragma unroll
    for (int nf=0;nf<4;++nf) {
      #pragma unroll
      for (int r=0;r<4;++r) {
        int row = by*256 + wm*128 + mf*16 + ((l>>4)<<2) + r;
        int col = bx*256 + wn*64 + nf*16 + rA;
        float v = acc[mf][nf][r] + bias[col];
        if constexpr (EPI==2) {
          float sv = v / (1.f + __expf(-v));
          ((short*)out1)[(size_t)row*N + col] = f2b(sv);
        } else {
          ((short*)out1)[(size_t)row*N + col] = f2b(v);
        }
      }
    }
  }
}

// -------------------- Flash attention over W=1024 keys --------------------
// 1 wave per workgroup (64 thr), 32 q-rows/wave, 4096 blocks, no barriers.
// K/V L2-resident. Scores in log2 domain (K pre-scaled by KSC) -> exp2.
struct KF { s16x8 v[4][2]; };

__global__ __launch_bounds__(64,2) void attn_kernel(const short* __restrict__ q,
    const short* __restrict__ kpan, const short* __restrict__ vtpan,
    const u64* __restrict__ pmarr, short* __restrict__ outp) {
  __shared__ short P[32*72];
  int l = threadIdx.x;
  int id = blockIdx.x;
  int xcd = id & 7, slot = id >> 3;
  int bh = xcd + 8*(slot >> 6);        // 0..63 (= b*16+h)
  int u  = 63 - (slot & 63);           // 32-row tile, heavy-first
  int bb = bh >> 4, h = bh & 15;
  int r0 = u*32;
  const short* kbase = kpan + (size_t)bh*WW*DHH;
  const short* vbase = vtpan + (size_t)bh*DHH*WW;
  u64 pmask = pmarr[bb*16 + (l&15)];
  const s16x8 ones8 = { 0x3F80,0x3F80,0x3F80,0x3F80,0x3F80,0x3F80,0x3F80,0x3F80 };

  s16x8 aq[2][2];
  #pragma unroll
  for (int g=0;g<2;++g)
    #pragma unroll
    for (int kf=0;kf<2;++kf)
      aq[g][kf] = *(const s16x8*)(q + ((size_t)bb*SS + r0 + g*16 + (l&15))*DD
                                    + h*DHH + (l>>4)*8 + kf*32);
  f32x4 oacc[2][4];
  float mrun[2][4], lrun[2][4], scale[2][4];
  #pragma unroll
  for (int g=0;g<2;++g)
    #pragma unroll
    for (int i=0;i<4;++i) {
      #pragma unroll
      for (int r=0;r<4;++r) oacc[g][i][r]=0.f;
      mrun[g][i]=-INFINITY; lrun[g][i]=0.f;
    }
  int dchunk = u>>1;
  int nch = dchunk+1 < 16 ? dchunk+1 : 16;

  auto loadK = [&](int c, KF& d) {
    const short* kc = kbase + (size_t)c*64*DHH;
    #pragma unroll
    for (int nf=0;nf<4;++nf) {
      const short* p = kc + (size_t)(nf*16+(l&15))*DHH + ((l>>4)*8);
      d.v[nf][0] = *(const s16x8*)p;
      d.v[nf][1] = *(const s16x8*)(p+32);
    }
  };

  auto body = [&](int c, KF& kf) {
    f32x4 sc[2][4];
    #pragma unroll
    for (int g=0;g<2;++g)
      #pragma unroll
      for (int nf=0;nf<4;++nf)
        #pragma unroll
        for (int r=0;r<4;++r) sc[g][nf][r]=0.f;
    __builtin_amdgcn_s_setprio(1);
    #pragma unroll
    for (int nf=0;nf<4;++nf)
      #pragma unroll
      for (int g=0;g<2;++g) {
        sc[g][nf] = mfma16(aq[g][0], kf.v[nf][0], sc[g][nf]);
        sc[g][nf] = mfma16(aq[g][1], kf.v[nf][1], sc[g][nf]);
      }
    __builtin_amdgcn_s_setprio(0);
    unsigned nib = (unsigned)(pmask >> (c*4)) & 15u;
    float pm[2][4];
    #pragma unroll
    for (int g=0;g<2;++g)
      #pragma unroll
      for (int r=0;r<4;++r) pm[g][r] = -INFINITY;
    if (c >= dchunk) {               // diagonal / future: pad + causal
      #pragma unroll
      for (int nf=0;nf<4;++nf) {
        int j = c*64 + nf*16 + (l&15);
        int padj = (int)((nib>>nf)&1u);
        #pragma unroll
        for (int g=0;g<2;++g)
          #pragma unroll
          for (int r=0;r<4;++r) {
            int sq_ = r0 + g*16 + ((l>>4)<<2) + r;
            float xv = (padj || (j > sq_)) ? NEGV : sc[g][nf][r];
            sc[g][nf][r] = xv;
            pm[g][r] = fmaxf(pm[g][r], xv);
          }
      }
    } else {                          // interior: pad-only
      #pragma unroll
      for (int nf=0;nf<4;++nf) {
        int padj = (int)((nib>>nf)&1u);
        #pragma unroll
        for (int g=0;g<2;++g)
          #pragma unroll
          for (int r=0;r<4;++r) {
            float xv = padj ? NEGV : sc[g][nf][r];
            sc[g][nf][r] = xv;
            pm[g][r] = fmaxf(pm[g][r], xv);
          }
      }
    }
    s16x8 vf0[4], vf1[4];
    #pragma unroll
    for (int nf=0;nf<4;++nf)
      vf0[nf] = *(const s16x8*)(vbase + (size_t)(nf*16+(l&15))*WW
                                + c*64 + ((l>>4)*8));
    int need = 0;
    #pragma unroll
    for (int g=0;g<2;++g)
      #pragma unroll
      for (int r=0;r<4;++r) need |= (pm[g][r] > mrun[g][r] + 12.f) ? 1 : 0;
    #pragma unroll
    for (int g=0;g<2;++g)
      #pragma unroll
      for (int r=0;r<4;++r) scale[g][r] = 1.f;
    if (__any(need)) {
      #pragma unroll
      for (int m=1;m<16;m<<=1)
        #pragma unroll
        for (int g=0;g<2;++g)
          #pragma unroll
          for (int r=0;r<4;++r) pm[g][r] = fmaxf(pm[g][r], __shfl_xor(pm[g][r], m));
      #pragma unroll
      for (int g=0;g<2;++g)
        #pragma unroll
        for (int r=0;r<4;++r) {
          float mn = fmaxf(mrun[g][r], pm[g][r]);
          scale[g][r] = exp2f(mrun[g][r]-mn);
          mrun[g][r] = mn;
        }
      #pragma unroll
      for (int g=0;g<2;++g)
        #pragma unroll
        for (int nf=0;nf<4;++nf)
          #pragma unroll
          for (int r=0;r<4;++r) oacc[g][nf][r] *= scale[g][r];
    }
    #pragma unroll
    for (int nf=0;nf<4;++nf)
      #pragma unroll
      for (int g=0;g<2;++g)
        #pragma unroll
        for (int r=0;r<4;++r)
          sc[g][nf][r] = exp2f(sc[g][nf][r]-mrun[g][r]);
    #pragma unroll
    for (int nf=0;nf<4;++nf)
      vf1[nf] = *(const s16x8*)(vbase + (size_t)(nf*16+(l&15))*WW
                                + c*64 + 32 + ((l>>4)*8));
    #pragma unroll
    for (int g=0;g<2;++g)
      #pragma unroll
      for (int nf=0;nf<4;++nf)
        #pragma unroll
        for (int r=0;r<4;++r)
          P[(g*16+((l>>4)<<2)+r)*72 + nf*16 + (l&15)] = f2b(sc[g][nf][r]);
    f32x4 ls2[2];
    #pragma unroll
    for (int g=0;g<2;++g)
      #pragma unroll
      for (int r=0;r<4;++r) ls2[g][r]=0.f;
    __builtin_amdgcn_s_setprio(1);
    #pragma unroll
    for (int ks=0;ks<2;++ks) {
      s16x8 ap[2];
      #pragma unroll
      for (int g=0;g<2;++g) {
        ap[g] = *(const s16x8*)&P[(g*16+(l&15))*72 + ks*32 + ((l>>4)*8)];
        ls2[g] = mfma16(ap[g], ones8, ls2[g]);
      }
      #pragma unroll
      for (int nf=0;nf<4;++nf) {
        s16x8 bv = ks ? vf1[nf] : vf0[nf];
        #pragma unroll
        for (int g=0;g<2;++g)
          oacc[g][nf] = mfma16(ap[g], bv, oacc[g][nf]);
      }
    }
    __builtin_amdgcn_s_setprio(0);
    #pragma unroll
    for (int g=0;g<2;++g)
      #pragma unroll
      for (int r=0;r<4;++r) lrun[g][r] = lrun[g][r]*scale[g][r] + ls2[g][r];
  };

  KF ka, kb;
  loadK(0, ka);
  int cend = nch, c = 0, ext = 0;
  while (true) {
    if (c == cend) {
      if (ext) break;
      ext = 1;
      int dead = 0;
      #pragma unroll
      for (int g=0;g<2;++g)
        #pragma unroll
        for (int r=0;r<4;++r) dead |= (mrun[g][r] < -5e9f) ? 1 : 0;
      if (!__any(dead)) break;
      cend = 16;
      if (c >= 16) break;
    }
    if (c+1 < 16) loadK(c+1, kb);   // prefetch next chunk's K (L2-hit)
    body(c, ka);
    ka = kb;
    ++c;
  }

  #pragma unroll
  for (int g=0;g<2;++g)
    #pragma unroll
    for (int nf=0;nf<4;++nf)
      #pragma unroll
      for (int r=0;r<4;++r) {
        int srow = r0 + g*16 + ((l>>4)<<2) + r;
        float o = oacc[g][nf][r] / lrun[g][r];
        outp[((size_t)bb*SS + srow)*DD + h*DHH + nf*16 + (l&15)] = f2b(o);
      }
}

// -------------------- driver --------------------
extern "C" void kernel_launch(void* const* d_in, const int* in_sizes, int n_in,
                              void* d_out, int out_size, void* d_ws, size_t ws_size,
                              hipStream_t stream) {
  const float* x    = (const float*)d_in[0];
  const int*   pad  = (const int*)d_in[1];   // bool mask as int32 on device
  const float* ln1g = (const float*)d_in[2];
  const float* ln1b = (const float*)d_in[3];
  const float* wq   = (const float*)d_in[4];
  const float* bq   = (const float*)d_in[5];
  const float* wkv  = (const float*)d_in[6];
  const float* bkv  = (const float*)d_in[7];
  const float* ln2g = (const float*)d_in[8];
  const float* ln2b = (const float*)d_in[9];
  const float* w1   = (const float*)d_in[10];
  const float* b1   = (const float*)d_in[11];
  const float* w2   = (const float*)d_in[12];
  const float* b2   = (const float*)d_in[13];

  char* ws = (char*)d_ws;
  const size_t MB = 1024*1024;
  short* ln1x = (short*)(ws + 0);        // 16MB, dead after KV gemm
  short* qb   = (short*)(ws + 16*MB);    // 16MB, dead after attn
  short* kpan = (short*)(ws + 32*MB);    //  8MB, dead after attn
  short* vtp  = (short*)(ws + 40*MB);    //  8MB, dead after attn
  u64*   pmar = (u64*)  (ws + 48*MB);    //  512B
  short* h1   = (short*)(ws + 0);        // 64MB, reuses [0,64MB) after attn
  short* outb = (short*)(ws + 64*MB);    // 16MB attn out
  short* hb   = (short*)(ws + 80*MB);    // 16MB ln2 out
  short* wqT  = (short*)(ws + 96*MB);    //  2MB
  short* wkvT = (short*)(ws + 98*MB);    //  4MB
  short* w1T  = (short*)(ws + 102*MB);   //  8MB
  short* w2T  = (short*)(ws + 110*MB);   //  8MB  (total 118MB)

  pad_bitmask<<<1,64,0,stream>>>(pad, pmar);
  transpose_cast<<<dim3(32,32),  256,0,stream>>>(wq,  wqT,  1024, 1024);
  transpose_cast<<<dim3(64,32),  256,0,stream>>>(wkv, wkvT, 1024, 2048);
  transpose_cast<<<dim3(128,32), 256,0,stream>>>(w1,  w1T,  1024, 4096);
  transpose_cast<<<dim3(32,128), 256,0,stream>>>(w2,  w2T,  4096, 1024);
  ln_kernel<0><<<MM,256,0,stream>>>(x, ln1g, ln1b, ln1x);
  gemm_bt<0><<<512, 256,0,stream>>>(ln1x, wqT,  bq,  qb,   nullptr, nullptr, 1024, 1024, 3);
  gemm_bt<1><<<512, 256,0,stream>>>(ln1x, wkvT, bkv, kpan, vtp,     nullptr, 2048, 1024, 4);
  attn_kernel<<<4096,64,0,stream>>>(qb, kpan, vtp, pmar, outb);
  ln_kernel<1><<<MM,256,0,stream>>>(outb, ln2g, ln2b, hb);
  gemm256<2><<<512,512,0,stream>>>(hb, w1T, b1, h1, 4096, 1024, 4);
  gemm_bt<3><<<512, 256,0,stream>>>(h1, w2T, b2, d_out, nullptr, x,       1024, 4096, 3);
}

// Round 8
// 366.054 us; speedup vs baseline: 1.7625x; 1.1020x over previous
//
#include <hip/hip_runtime.h>
#include <hip/hip_bf16.h>

// CustomTransformerBlock: B=4,S=2048,D=1024,H=16,DH=64,W=1024,DFF=4096
#define BB 4
#define SS 2048
#define DD 1024
#define HH 16
#define DHH 64
#define WW 1024
#define DFF 4096
#define MM (BB*SS)
#define NEGV (-1e10f)
// K pre-scale: log2(e)/sqrt(1024) folded into K at KV-GEMM epilogue
#define KSC 0.045084220027780106f

using f32x4 = __attribute__((ext_vector_type(4))) float;
using s16x8 = __attribute__((ext_vector_type(8))) short;
using s16x4 = __attribute__((ext_vector_type(4))) short;
using u64 = unsigned long long;

typedef const __attribute__((address_space(1))) void* gas_t;
typedef __attribute__((address_space(3))) void* las_t;

__device__ inline short f2b(float f) {
  __hip_bfloat16 h = __float2bfloat16(f);
  return __builtin_bit_cast(short, h);
}
__device__ inline float b2f(short u) {
  __hip_bfloat16 h = __builtin_bit_cast(__hip_bfloat16, u);
  return __bfloat162float(h);
}

__device__ inline void gload_lds16(const short* g, short* lds) {
  __builtin_amdgcn_global_load_lds((gas_t)g, (las_t)lds, 16, 0, 0);
}

__device__ inline f32x4 mfma16(s16x8 a, s16x8 b, f32x4 c) {
  return __builtin_amdgcn_mfma_f32_16x16x32_bf16(a, b, c, 0, 0, 0);
}

// -------------------- LayerNorm (row of 1024), out bf16 --------------------
template<int IN_BF16>
__global__ __launch_bounds__(256) void ln_kernel(const void* __restrict__ inp,
                                                 const float* __restrict__ g,
                                                 const float* __restrict__ bta,
                                                 short* __restrict__ outp) {
  int row = blockIdx.x;
  int t = threadIdx.x;
  float v[4];
  if constexpr (IN_BF16) {
    s16x4 r4 = *((const s16x4*)((const short*)inp + (size_t)row*DD) + t);
    v[0]=b2f(r4[0]); v[1]=b2f(r4[1]); v[2]=b2f(r4[2]); v[3]=b2f(r4[3]);
  } else {
    f32x4 r4 = *((const f32x4*)((const float*)inp + (size_t)row*DD) + t);
    v[0]=r4[0]; v[1]=r4[1]; v[2]=r4[2]; v[3]=r4[3];
  }
  float s = v[0]+v[1]+v[2]+v[3];
  float sq = v[0]*v[0]+v[1]*v[1]+v[2]*v[2]+v[3]*v[3];
  for (int m=1;m<64;m<<=1){ s += __shfl_xor(s,m); sq += __shfl_xor(sq,m); }
  __shared__ float red[8];
  int wv = t>>6;
  if ((t&63)==0){ red[wv]=s; red[4+wv]=sq; }
  __syncthreads();
  s  = red[0]+red[1]+red[2]+red[3];
  sq = red[4]+red[5]+red[6]+red[7];
  float mean = s*(1.f/DD);
  float rstd = rsqrtf(sq*(1.f/DD) - mean*mean + 1e-5f);
  int col = t*4;
  s16x4 o;
  #pragma unroll
  for (int j=0;j<4;++j) o[j] = f2b((v[j]-mean)*rstd*g[col+j]+bta[col+j]);
  *((s16x4*)(outp + (size_t)row*DD) + t) = o;
}

// ------------- fp32 [K][N] -> bf16 [N][K] transpose-cast (weights) ----------
__global__ __launch_bounds__(256) void transpose_cast(const float* __restrict__ in,
                                                      short* __restrict__ out,
                                                      int K, int N) {
  __shared__ float tile[32][33];
  int n0 = blockIdx.x*32, k0 = blockIdx.y*32;
  int tx = threadIdx.x & 31, ty = threadIdx.x >> 5;
  #pragma unroll
  for (int j=0;j<4;++j) tile[ty+8*j][tx] = in[(size_t)(k0+ty+8*j)*N + n0+tx];
  __syncthreads();
  #pragma unroll
  for (int j=0;j<4;++j) out[(size_t)(n0+ty+8*j)*K + k0+tx] = f2b(tile[tx][ty+8*j]);
}

// ---- pad bool(int) -> per-(b,col16) u64 bitmask: bit(c*4+nf) = pad[c*64+nf*16+col16]
__global__ void pad_bitmask(const int* __restrict__ pad, u64* __restrict__ pm) {
  int idx = threadIdx.x;            // 64 threads: b(2b) x col16(4b)
  int b_ = idx>>4, col = idx&15;
  const int* pb = pad + b_*SS + (SS-WW);
  u64 m = 0;
  for (int c=0;c<16;++c)
    for (int nf=0;nf<4;++nf)
      if (pb[c*64+nf*16+col]) m |= (1ull << (c*4+nf));
  pm[idx] = m;
}

// ---------- 256x256 8-wave GEMM, BK=32, 4-phase counted-vmcnt schedule ------
// (proven in R7: FF1 129->~95us). Regions A0|B0|A1|B1 16KB each, 64KB LDS.
template<int EPI>
__global__ __launch_bounds__(512) void gemm256(const short* __restrict__ A,
                                               const short* __restrict__ Bt,
                                               const float* __restrict__ bias,
                                               void* __restrict__ out1,
                                               int N, int K, int lgx) {
  __shared__ short lds[32768];   // 64KB
  int tid = threadIdx.x, l = tid&63, wid = tid>>6;
  int wm = wid>>2, wn = wid&3;
  int q8 = gridDim.x >> 3;
  int wg = (blockIdx.x & 7)*q8 + (blockIdx.x >> 3);
  int bx = wg & ((1<<lgx)-1), by = wg >> lgx;
  const short* Ablk = A + (size_t)by*256*K;
  const short* Bblk = Bt + (size_t)bx*256*K;
  int rA = l & 15;
  int slot_s = ((l>>4) ^ ((rA>>1)&3))*8;
  int aBase = (wm*128 + rA)*32 + slot_s;
  int bBase = (wn*64  + rA)*32 + slot_s + 8192;
  int qs = (tid&3) ^ ((tid>>3)&3);
  const short* srcA = Ablk + (size_t)(tid>>2)*K + qs*8;
  const short* srcB = Bblk + (size_t)(tid>>2)*K + qs*8;
  int dst0 = (tid & ~63)*8;
  int nt = K >> 5;
  f32x4 acc[8][4];
  #pragma unroll
  for (int i=0;i<8;++i)
    #pragma unroll
    for (int j=0;j<4;++j)
      #pragma unroll
      for (int r=0;r<4;++r) acc[i][j][r]=0.f;

  auto stage = [&](int isB, int b, int t) {
    const short* s = isB ? srcB : srcA;
    short* d = &lds[b*16384 + isB*8192 + dst0];
    gload_lds16(s + t*32,                 d);
    gload_lds16(s + (size_t)128*K + t*32, d + 4096);
  };
  s16x8 af[4], bf[4];
  auto readA = [&](int b, int mg) {
    #pragma unroll
    for (int j=0;j<4;++j) af[j] = *(const s16x8*)&lds[b*16384 + aBase + (mg*4+j)*512];
  };
  auto readB = [&](int b) {
    #pragma unroll
    for (int j=0;j<4;++j) bf[j] = *(const s16x8*)&lds[b*16384 + bBase + j*512];
  };
  auto mfmas = [&](int mg) {
    __builtin_amdgcn_s_setprio(1);
    #pragma unroll
    for (int j=0;j<4;++j)
      #pragma unroll
      for (int nf=0;nf<4;++nf)
        acc[mg*4+j][nf] = mfma16(af[j], bf[nf], acc[mg*4+j][nf]);
    __builtin_amdgcn_s_setprio(0);
  };

  stage(0,0,0); stage(1,0,0); stage(1,1,1);
  asm volatile("s_waitcnt vmcnt(2)" ::: "memory");
  __builtin_amdgcn_s_barrier();

  for (int it = 0; it < (nt>>1); ++it) {
    int t0 = 2*it;
    int t2 = t0+2; if (t2 >= nt) t2 -= nt;
    int t3 = t0+3; if (t3 >= nt) t3 -= nt;
    readB(0); readA(0,0);
    stage(0,1,t0+1);
    __builtin_amdgcn_s_barrier();
    mfmas(0);
    __builtin_amdgcn_s_barrier();
    readA(0,1);
    stage(1,0,t2);
    __builtin_amdgcn_s_barrier();
    mfmas(1);
    asm volatile("s_waitcnt vmcnt(2)" ::: "memory");
    __builtin_amdgcn_s_barrier();
    readB(1); readA(1,0);
    stage(0,0,t2);
    __builtin_amdgcn_s_barrier();
    mfmas(0);
    __builtin_amdgcn_s_barrier();
    readA(1,1);
    stage(1,1,t3);
    __builtin_amdgcn_s_barrier();
    mfmas(1);
    asm volatile("s_waitcnt vmcnt(2)" ::: "memory");
    __builtin_amdgcn_s_barrier();
  }
  asm volatile("s_waitcnt vmcnt(0)" ::: "memory");

  #pragma unroll
  for (int mf=0;mf<8;++mf) {
    #pragma unroll
    for (int nf=0;nf<4;++nf) {
      #pragma unroll
      for (int r=0;r<4;++r) {
        int row = by*256 + wm*128 + mf*16 + ((l>>4)<<2) + r;
        int col = bx*256 + wn*64 + nf*16 + rA;
        float v = acc[mf][nf][r] + bias[col];
        if constexpr (EPI==2) {
          float sv = v / (1.f + __expf(-v));
          ((short*)out1)[(size_t)row*N + col] = f2b(sv);
        } else {
          ((short*)out1)[(size_t)row*N + col] = f2b(v);
        }
      }
    }
  }
}

// ---------- 256x128 8-wave GEMM, BK=32, 4-phase counted-vmcnt schedule ------
// For N=1024/2048 GEMMs (Q, KV, FF2): 256-wg grids. Regions A=16KB, B=8KB,
// dbuf = 48KB LDS. Staging per K-tile: A=2 loads/thr, B=1 load/thr.
// Rotation: ph0 stages A(b1,t0+1); ph1 B(b0,t0+2) then vmcnt(1) [completes
// b1's A+B]; ph2 A(b0,t0+2); ph3 B(b1,t0+3) then vmcnt(1) [completes b0].
// Every region staged >=2 phases before its read with a vmcnt checkpoint +
// barrier in between; vmcnt never drained to 0 inside the loop (T4).
// EPI: 0=q(bf16), 1=kv(K*KSC + V transposed), 3=ff2(f32 +resid)
template<int EPI>
__global__ __launch_bounds__(512) void gemm256x128(const short* __restrict__ A,
                                                   const short* __restrict__ Bt,
                                                   const float* __restrict__ bias,
                                                   void* __restrict__ out1,
                                                   void* __restrict__ out2,
                                                   const float* __restrict__ resid,
                                                   int N, int K, int lgx) {
  __shared__ short lds[24576];   // 48KB: [A0 16KB][B0 8KB][A1 16KB][B1 8KB]
  int tid = threadIdx.x, l = tid&63, wid = tid>>6;
  int wm = wid>>1, wn = wid&1;
  int q8 = gridDim.x >> 3;
  int wg = (blockIdx.x & 7)*q8 + (blockIdx.x >> 3);
  int bx = wg & ((1<<lgx)-1), by = wg >> lgx;
  const short* Ablk;
  if constexpr (EPI==1) {
    int b_ = (by*256)>>10, w0 = (by*256)&1023;   // 1024%256==0: tile in one batch
    Ablk = A + ((size_t)b_*SS + (SS-WW) + w0)*DD;
  } else {
    Ablk = A + (size_t)by*256*K;
  }
  const short* Bblk = Bt + (size_t)bx*128*K;
  int rA = l & 15;
  int slot_s = ((l>>4) ^ ((rA>>1)&3))*8;
  int aBase = (wm*64 + rA)*32 + slot_s;
  int bBase = 8192 + (wn*64 + rA)*32 + slot_s;
  int qs = (tid&3) ^ ((tid>>3)&3);
  const short* srcA = Ablk + (size_t)(tid>>2)*K + qs*8;
  const short* srcB = Bblk + (size_t)(tid>>2)*K + qs*8;
  int dst0 = (tid & ~63)*8;
  int nt = K >> 5;
  f32x4 acc[4][4];
  #pragma unroll
  for (int i=0;i<4;++i)
    #pragma unroll
    for (int j=0;j<4;++j)
      #pragma unroll
      for (int r=0;r<4;++r) acc[i][j][r]=0.f;

  auto stageA = [&](int b, int t) {
    short* d = &lds[b*12288 + dst0];
    gload_lds16(srcA + t*32,                 d);
    gload_lds16(srcA + (size_t)128*K + t*32, d + 4096);
  };
  auto stageB = [&](int b, int t) {
    gload_lds16(srcB + t*32, &lds[b*12288 + 8192 + dst0]);
  };
  s16x8 af[2], bf[4];
  auto readA = [&](int b, int mg) {
    #pragma unroll
    for (int j=0;j<2;++j) af[j] = *(const s16x8*)&lds[b*12288 + aBase + (mg*2+j)*512];
  };
  auto readB = [&](int b) {
    #pragma unroll
    for (int j=0;j<4;++j) bf[j] = *(const s16x8*)&lds[b*12288 + bBase + j*512];
  };
  auto mfmas = [&](int mg) {
    __builtin_amdgcn_s_setprio(1);
    #pragma unroll
    for (int j=0;j<2;++j)
      #pragma unroll
      for (int nf=0;nf<4;++nf)
        acc[mg*2+j][nf] = mfma16(af[j], bf[nf], acc[mg*2+j][nf]);
    __builtin_amdgcn_s_setprio(0);
  };

  // prologue: A(b0,0), B(b0,0), B(b1,1) = 4 loads; vmcnt(1) -> b0 ready
  stageA(0,0); stageB(0,0); stageB(1,1);
  asm volatile("s_waitcnt vmcnt(1)" ::: "memory");
  __builtin_amdgcn_s_barrier();

  for (int it = 0; it < (nt>>1); ++it) {
    int t0 = 2*it;
    int t2 = t0+2; if (t2 >= nt) t2 -= nt;   // tail stages wrap (never read)
    int t3 = t0+3; if (t3 >= nt) t3 -= nt;
    // ph0: tile t0 (b0), frags mg0
    readB(0); readA(0,0);
    stageA(1,t0+1);
    __builtin_amdgcn_s_barrier();
    mfmas(0);
    __builtin_amdgcn_s_barrier();
    // ph1: (b0) mg1
    readA(0,1);
    stageB(0,t2);
    __builtin_amdgcn_s_barrier();
    mfmas(1);
    asm volatile("s_waitcnt vmcnt(1)" ::: "memory");   // b1 A+B complete
    __builtin_amdgcn_s_barrier();
    // ph2: tile t0+1 (b1), mg0
    readB(1); readA(1,0);
    stageA(0,t2);
    __builtin_amdgcn_s_barrier();
    mfmas(0);
    __builtin_amdgcn_s_barrier();
    // ph3: (b1) mg1
    readA(1,1);
    stageB(1,t3);
    __builtin_amdgcn_s_barrier();
    mfmas(1);
    asm volatile("s_waitcnt vmcnt(1)" ::: "memory");   // b0 A+B complete
    __builtin_amdgcn_s_barrier();
  }
  asm volatile("s_waitcnt vmcnt(0)" ::: "memory");

  #pragma unroll
  for (int mf=0;mf<4;++mf) {
    #pragma unroll
    for (int nf=0;nf<4;++nf) {
      #pragma unroll
      for (int r=0;r<4;++r) {
        int row = by*256 + wm*64 + mf*16 + ((l>>4)<<2) + r;
        int col = bx*128 + wn*64 + nf*16 + rA;
        float v = acc[mf][nf][r] + bias[col];
        if constexpr (EPI==0) {
          ((short*)out1)[(size_t)row*N + col] = f2b(v);
        } else if constexpr (EPI==1) {
          int b_ = row>>10, w_ = row&1023;
          if (col < DD) {        // K head: [b][h][w][dh], pre-scaled by KSC
            int h = col>>6, dh = col&63;
            ((short*)out1)[(((size_t)(b_*HH+h))*WW + w_)*DHH + dh] = f2b(v*KSC);
          } else {               // V head transposed: [b][h][dh][w]
            int cc = col - DD;
            int h = cc>>6, dh = cc&63;
            ((short*)out2)[(((size_t)(b_*HH+h))*DHH + dh)*WW + w_] = f2b(v);
          }
        } else {
          ((float*)out1)[(size_t)row*N + col] = v + resid[(size_t)row*N + col];
        }
      }
    }
  }
}

// -------------------- Flash attention over W=1024 keys --------------------
// 1 wave per workgroup (64 thr), 32 q-rows/wave, 4096 blocks, no barriers.
// K/V L2-resident. Scores in log2 domain (K pre-scaled by KSC) -> exp2.
struct KF { s16x8 v[4][2]; };

__global__ __launch_bounds__(64,2) void attn_kernel(const short* __restrict__ q,
    const short* __restrict__ kpan, const short* __restrict__ vtpan,
    const u64* __restrict__ pmarr, short* __restrict__ outp) {
  __shared__ short P[32*72];
  int l = threadIdx.x;
  int id = blockIdx.x;
  int xcd = id & 7, slot = id >> 3;
  int bh = xcd + 8*(slot >> 6);        // 0..63 (= b*16+h)
  int u  = 63 - (slot & 63);           // 32-row tile, heavy-first
  int bb = bh >> 4, h = bh & 15;
  int r0 = u*32;
  const short* kbase = kpan + (size_t)bh*WW*DHH;
  const short* vbase = vtpan + (size_t)bh*DHH*WW;
  u64 pmask = pmarr[bb*16 + (l&15)];
  const s16x8 ones8 = { 0x3F80,0x3F80,0x3F80,0x3F80,0x3F80,0x3F80,0x3F80,0x3F80 };

  s16x8 aq[2][2];
  #pragma unroll
  for (int g=0;g<2;++g)
    #pragma unroll
    for (int kf=0;kf<2;++kf)
      aq[g][kf] = *(const s16x8*)(q + ((size_t)bb*SS + r0 + g*16 + (l&15))*DD
                                    + h*DHH + (l>>4)*8 + kf*32);
  f32x4 oacc[2][4];
  float mrun[2][4], lrun[2][4], scale[2][4];
  #pragma unroll
  for (int g=0;g<2;++g)
    #pragma unroll
    for (int i=0;i<4;++i) {
      #pragma unroll
      for (int r=0;r<4;++r) oacc[g][i][r]=0.f;
      mrun[g][i]=-INFINITY; lrun[g][i]=0.f;
    }
  int dchunk = u>>1;
  int nch = dchunk+1 < 16 ? dchunk+1 : 16;

  auto loadK = [&](int c, KF& d) {
    const short* kc = kbase + (size_t)c*64*DHH;
    #pragma unroll
    for (int nf=0;nf<4;++nf) {
      const short* p = kc + (size_t)(nf*16+(l&15))*DHH + ((l>>4)*8);
      d.v[nf][0] = *(const s16x8*)p;
      d.v[nf][1] = *(const s16x8*)(p+32);
    }
  };

  auto body = [&](int c, KF& kf) {
    f32x4 sc[2][4];
    #pragma unroll
    for (int g=0;g<2;++g)
      #pragma unroll
      for (int nf=0;nf<4;++nf)
        #pragma unroll
        for (int r=0;r<4;++r) sc[g][nf][r]=0.f;
    __builtin_amdgcn_s_setprio(1);
    #pragma unroll
    for (int nf=0;nf<4;++nf)
      #pragma unroll
      for (int g=0;g<2;++g) {
        sc[g][nf] = mfma16(aq[g][0], kf.v[nf][0], sc[g][nf]);
        sc[g][nf] = mfma16(aq[g][1], kf.v[nf][1], sc[g][nf]);
      }
    __builtin_amdgcn_s_setprio(0);
    unsigned nib = (unsigned)(pmask >> (c*4)) & 15u;
    float pm[2][4];
    #pragma unroll
    for (int g=0;g<2;++g)
      #pragma unroll
      for (int r=0;r<4;++r) pm[g][r] = -INFINITY;
    if (c >= dchunk) {               // diagonal / future: pad + causal
      #pragma unroll
      for (int nf=0;nf<4;++nf) {
        int j = c*64 + nf*16 + (l&15);
        int padj = (int)((nib>>nf)&1u);
        #pragma unroll
        for (int g=0;g<2;++g)
          #pragma unroll
          for (int r=0;r<4;++r) {
            int sq_ = r0 + g*16 + ((l>>4)<<2) + r;
            float xv = (padj || (j > sq_)) ? NEGV : sc[g][nf][r];
            sc[g][nf][r] = xv;
            pm[g][r] = fmaxf(pm[g][r], xv);
          }
      }
    } else {                          // interior: pad-only
      #pragma unroll
      for (int nf=0;nf<4;++nf) {
        int padj = (int)((nib>>nf)&1u);
        #pragma unroll
        for (int g=0;g<2;++g)
          #pragma unroll
          for (int r=0;r<4;++r) {
            float xv = padj ? NEGV : sc[g][nf][r];
            sc[g][nf][r] = xv;
            pm[g][r] = fmaxf(pm[g][r], xv);
          }
      }
    }
    s16x8 vf0[4], vf1[4];
    #pragma unroll
    for (int nf=0;nf<4;++nf)
      vf0[nf] = *(const s16x8*)(vbase + (size_t)(nf*16+(l&15))*WW
                                + c*64 + ((l>>4)*8));
    int need = 0;
    #pragma unroll
    for (int g=0;g<2;++g)
      #pragma unroll
      for (int r=0;r<4;++r) need |= (pm[g][r] > mrun[g][r] + 12.f) ? 1 : 0;
    #pragma unroll
    for (int g=0;g<2;++g)
      #pragma unroll
      for (int r=0;r<4;++r) scale[g][r] = 1.f;
    if (__any(need)) {
      #pragma unroll
      for (int m=1;m<16;m<<=1)
        #pragma unroll
        for (int g=0;g<2;++g)
          #pragma unroll
          for (int r=0;r<4;++r) pm[g][r] = fmaxf(pm[g][r], __shfl_xor(pm[g][r], m));
      #pragma unroll
      for (int g=0;g<2;++g)
        #pragma unroll
        for (int r=0;r<4;++r) {
          float mn = fmaxf(mrun[g][r], pm[g][r]);
          scale[g][r] = exp2f(mrun[g][r]-mn);
          mrun[g][r] = mn;
        }
      #pragma unroll
      for (int g=0;g<2;++g)
        #pragma unroll
        for (int nf=0;nf<4;++nf)
          #pragma unroll
          for (int r=0;r<4;++r) oacc[g][nf][r] *= scale[g][r];
    }
    #pragma unroll
    for (int nf=0;nf<4;++nf)
      #pragma unroll
      for (int g=0;g<2;++g)
        #pragma unroll
        for (int r=0;r<4;++r)
          sc[g][nf][r] = exp2f(sc[g][nf][r]-mrun[g][r]);
    #pragma unroll
    for (int nf=0;nf<4;++nf)
      vf1[nf] = *(const s16x8*)(vbase + (size_t)(nf*16+(l&15))*WW
                                + c*64 + 32 + ((l>>4)*8));
    #pragma unroll
    for (int g=0;g<2;++g)
      #pragma unroll
      for (int nf=0;nf<4;++nf)
        #pragma unroll
        for (int r=0;r<4;++r)
          P[(g*16+((l>>4)<<2)+r)*72 + nf*16 + (l&15)] = f2b(sc[g][nf][r]);
    f32x4 ls2[2];
    #pragma unroll
    for (int g=0;g<2;++g)
      #pragma unroll
      for (int r=0;r<4;++r) ls2[g][r]=0.f;
    __builtin_amdgcn_s_setprio(1);
    #pragma unroll
    for (int ks=0;ks<2;++ks) {
      s16x8 ap[2];
      #pragma unroll
      for (int g=0;g<2;++g) {
        ap[g] = *(const s16x8*)&P[(g*16+(l&15))*72 + ks*32 + ((l>>4)*8)];
        ls2[g] = mfma16(ap[g], ones8, ls2[g]);
      }
      #pragma unroll
      for (int nf=0;nf<4;++nf) {
        s16x8 bv = ks ? vf1[nf] : vf0[nf];
        #pragma unroll
        for (int g=0;g<2;++g)
          oacc[g][nf] = mfma16(ap[g], bv, oacc[g][nf]);
      }
    }
    __builtin_amdgcn_s_setprio(0);
    #pragma unroll
    for (int g=0;g<2;++g)
      #pragma unroll
      for (int r=0;r<4;++r) lrun[g][r] = lrun[g][r]*scale[g][r] + ls2[g][r];
  };

  KF ka, kb;
  loadK(0, ka);
  int cend = nch, c = 0, ext = 0;
  while (true) {
    if (c == cend) {
      if (ext) break;
      ext = 1;
      int dead = 0;
      #pragma unroll
      for (int g=0;g<2;++g)
        #pragma unroll
        for (int r=0;r<4;++r) dead |= (mrun[g][r] < -5e9f) ? 1 : 0;
      if (!__any(dead)) break;
      cend = 16;
      if (c >= 16) break;
    }
    if (c+1 < 16) loadK(c+1, kb);   // prefetch next chunk's K (L2-hit)
    body(c, ka);
    ka = kb;
    ++c;
  }

  #pragma unroll
  for (int g=0;g<2;++g)
    #pragma unroll
    for (int nf=0;nf<4;++nf)
      #pragma unroll
      for (int r=0;r<4;++r) {
        int srow = r0 + g*16 + ((l>>4)<<2) + r;
        float o = oacc[g][nf][r] / lrun[g][r];
        outp[((size_t)bb*SS + srow)*DD + h*DHH + nf*16 + (l&15)] = f2b(o);
      }
}

// -------------------- driver --------------------
extern "C" void kernel_launch(void* const* d_in, const int* in_sizes, int n_in,
                              void* d_out, int out_size, void* d_ws, size_t ws_size,
                              hipStream_t stream) {
  const float* x    = (const float*)d_in[0];
  const int*   pad  = (const int*)d_in[1];   // bool mask as int32 on device
  const float* ln1g = (const float*)d_in[2];
  const float* ln1b = (const float*)d_in[3];
  const float* wq   = (const float*)d_in[4];
  const float* bq   = (const float*)d_in[5];
  const float* wkv  = (const float*)d_in[6];
  const float* bkv  = (const float*)d_in[7];
  const float* ln2g = (const float*)d_in[8];
  const float* ln2b = (const float*)d_in[9];
  const float* w1   = (const float*)d_in[10];
  const float* b1   = (const float*)d_in[11];
  const float* w2   = (const float*)d_in[12];
  const float* b2   = (const float*)d_in[13];

  char* ws = (char*)d_ws;
  const size_t MB = 1024*1024;
  short* ln1x = (short*)(ws + 0);        // 16MB, dead after KV gemm
  short* qb   = (short*)(ws + 16*MB);    // 16MB, dead after attn
  short* kpan = (short*)(ws + 32*MB);    //  8MB, dead after attn
  short* vtp  = (short*)(ws + 40*MB);    //  8MB, dead after attn
  u64*   pmar = (u64*)  (ws + 48*MB);    //  512B
  short* h1   = (short*)(ws + 0);        // 64MB, reuses [0,64MB) after attn
  short* outb = (short*)(ws + 64*MB);    // 16MB attn out
  short* hb   = (short*)(ws + 80*MB);    // 16MB ln2 out
  short* wqT  = (short*)(ws + 96*MB);    //  2MB
  short* wkvT = (short*)(ws + 98*MB);    //  4MB
  short* w1T  = (short*)(ws + 102*MB);   //  8MB
  short* w2T  = (short*)(ws + 110*MB);   //  8MB  (total 118MB)

  pad_bitmask<<<1,64,0,stream>>>(pad, pmar);
  transpose_cast<<<dim3(32,32),  256,0,stream>>>(wq,  wqT,  1024, 1024);
  transpose_cast<<<dim3(64,32),  256,0,stream>>>(wkv, wkvT, 1024, 2048);
  transpose_cast<<<dim3(128,32), 256,0,stream>>>(w1,  w1T,  1024, 4096);
  transpose_cast<<<dim3(32,128), 256,0,stream>>>(w2,  w2T,  4096, 1024);
  ln_kernel<0><<<MM,256,0,stream>>>(x, ln1g, ln1b, ln1x);
  gemm256x128<0><<<256,512,0,stream>>>(ln1x, wqT,  bq,  qb,   nullptr, nullptr, 1024, 1024, 3);
  gemm256x128<1><<<256,512,0,stream>>>(ln1x, wkvT, bkv, kpan, vtp,     nullptr, 2048, 1024, 4);
  attn_kernel<<<4096,64,0,stream>>>(qb, kpan, vtp, pmar, outb);
  ln_kernel<1><<<MM,256,0,stream>>>(outb, ln2g, ln2b, hb);
  gemm256<2><<<512,512,0,stream>>>(hb, w1T, b1, h1, 4096, 1024, 4);
  gemm256x128<3><<<256,512,0,stream>>>(h1, w2T, b2, d_out, nullptr, x, 1024, 4096, 3);
}